// Round 5
// baseline (259.303 us; speedup 1.0000x reference)
//
#include <hip/hip_runtime.h>
#include <hip/hip_bf16.h>

// Problem constants (fixed by reference)
#define N_NODES 20000
#define NUM_DRUGS 2048
#define N_PROT (N_NODES - NUM_DRUGS)
#define NUM_DPI 200000
#define E2 400000          // 2*NUM_DPI directed edges
#define CDIM 256           // IN_C == EMB == 256
#define HID 512
#define N_CL 8
#define BATCH 16384
#define HN 8192            // H cols = 8 experts x 2 halves x 512

#define STRD 32            // drug counter padding (ints) = 1 line per counter
#define STRP 16            // protein counter padding
#define ELLD 192           // drug ELL stride (mean deg 97.7, +9.5 sigma)
#define ELLP 48            // protein ELL stride (mean deg 11.1, +11 sigma)

// fused-prep block ranges
#define NB_T64 512         // W1 transpose: 4 x 8 x 16
#define NB_TWG 32          // Wg1/Wg2 transpose: 4 x 4 x 2
#define NB_ZERO 79         // counter zeroing
#define NB_SPLIT 20000     // x split: 5.12M / 256

// node-GEMM tiling (BM=64): 313 row tiles
#define MT_NODE 313

// aggregate1 grid split
#define NB_AGG_D NUM_DRUGS              // 1 block per drug (4 waves)
#define NB_AGG_P ((N_PROT + 3) / 4)     // 4 proteins per block (1 wave each)

typedef __attribute__((ext_vector_type(8))) short short8;   // 8 bf16 (MFMA A/B frag)
typedef __attribute__((ext_vector_type(4))) float floatx4;  // MFMA C/D frag

__device__ inline unsigned short f2bf(float f) {
    unsigned u = __float_as_uint(f);
    u += 0x7fff + ((u >> 16) & 1);   // RNE
    return (unsigned short)(u >> 16);
}
__device__ inline float bf2f(unsigned short h) {
    return __uint_as_float((unsigned)h << 16);
}
__device__ inline void split2(float v, unsigned short& h, unsigned short& l) {
    h = f2bf(v);
    l = f2bf(v - bf2f(h));
}
__device__ inline void gload16(const void* g, void* l) {
    __builtin_amdgcn_global_load_lds(
        (const __attribute__((address_space(1))) void*)g,
        (__attribute__((address_space(3))) void*)l, 16, 0, 0);
}
__device__ inline float4 f4fma(float4 v, float s, float4 a) {
    a.x = fmaf(v.x, s, a.x); a.y = fmaf(v.y, s, a.y);
    a.z = fmaf(v.z, s, a.z); a.w = fmaf(v.w, s, a.w);
    return a;
}
__device__ inline float4 bf4(const unsigned short* p) {
    ushort4 q = *(const ushort4*)p;
    return make_float4(bf2f(q.x), bf2f(q.y), bf2f(q.z), bf2f(q.w));
}

// ---------------------------------------------------------------------------
// Fused prep: W1 transpose-split | Wg1/Wg2 transpose-split | counter zero |
// x split. All mutually independent; one dispatch instead of four.
__global__ __launch_bounds__(256) void prep_all(
        const float* __restrict__ x, unsigned short* __restrict__ xhi,
        unsigned short* __restrict__ xlo,
        const float* __restrict__ Wg1, const float* __restrict__ Wg2,
        unsigned short* __restrict__ wg1Th, unsigned short* __restrict__ wg1Tl,
        unsigned short* __restrict__ wg2Th, unsigned short* __restrict__ wg2Tl,
        const float* __restrict__ W1, unsigned short* __restrict__ W1Th,
        unsigned short* __restrict__ W1Tl,
        int* __restrict__ cur_d, int* __restrict__ cur_p) {
    __shared__ float ld[64 * 65];
    int b = blockIdx.x;
    int t = threadIdx.x;
    int tx = t & 63, ty = t >> 6;
    if (b < NB_T64) {
        // W1 [16 slabs][256][512] -> W1cat^T [8192][256] split bf16
        int m = b >> 5;
        int k0 = (b & 3) * 64, n0 = ((b >> 2) & 7) * 64;
        const float* Wm = W1 + (size_t)m * CDIM * HID;
#pragma unroll
        for (int rr = 0; rr < 16; rr++) {
            int kl = rr * 4 + ty;
            ld[tx * 65 + kl] = Wm[(size_t)(k0 + kl) * HID + n0 + tx];
        }
        __syncthreads();
        size_t obase = (size_t)m * HID * CDIM;
#pragma unroll
        for (int rr = 0; rr < 16; rr++) {
            int nl = rr * 4 + ty;
            float v = ld[nl * 65 + tx];
            unsigned short h, l;
            split2(v, h, l);
            size_t o = obase + (size_t)(n0 + nl) * CDIM + k0 + tx;
            W1Th[o] = h;
            W1Tl[o] = l;
        }
        return;
    }
    b -= NB_T64;
    if (b < NB_TWG) {
        // Wg1/Wg2 [256][256] -> transposed split bf16
        const float* W = (b >> 4) ? Wg2 : Wg1;
        unsigned short* hi = (b >> 4) ? wg2Th : wg1Th;
        unsigned short* lo = (b >> 4) ? wg2Tl : wg1Tl;
        int k0 = (b & 3) * 64, n0 = ((b >> 2) & 3) * 64;
#pragma unroll
        for (int rr = 0; rr < 16; rr++) {
            int kl = rr * 4 + ty;
            ld[tx * 65 + kl] = W[(size_t)(k0 + kl) * CDIM + n0 + tx];
        }
        __syncthreads();
#pragma unroll
        for (int rr = 0; rr < 16; rr++) {
            int nl = rr * 4 + ty;
            float v = ld[nl * 65 + tx];
            unsigned short h, l;
            split2(v, h, l);
            size_t o = (size_t)(n0 + nl) * CDIM + k0 + tx;
            hi[o] = h;
            lo[o] = l;
        }
        return;
    }
    b -= NB_TWG;
    if (b < NB_ZERO) {
        int i = b * 256 + t;
        if (i < N_NODES) cur_p[i * STRP] = 0;
        if (i < NUM_DRUGS) cur_d[i * STRD] = 0;
        return;
    }
    b -= NB_ZERO;
    {   // x split: exactly NB_SPLIT blocks cover 5.12M elems
        int i = b * 256 + t;
        unsigned short h, l;
        split2(x[i], h, l);
        xhi[i] = h;
        xlo[i] = l;
    }
}

// fill both ELL adjacency lists directly (no count/scan passes needed)
__global__ void fill_ell(const int* __restrict__ ei, int* cur_d, int* adj_drug,
                         int* cur_p, int* adj_prot) {
    int e = blockIdx.x * blockDim.x + threadIdx.x;
    if (e >= NUM_DPI) return;
    int d = ei[e];
    int p = ei[E2 + e];
    int posd = atomicAdd(&cur_d[d * STRD], 1);
    int posp = atomicAdd(&cur_p[p * STRP], 1);
    if (posd < ELLD) adj_drug[d * ELLD + posd] = p;   // clamp: never corrupt neighbor
    if (posp < ELLP) adj_prot[(size_t)p * ELLP + posp] = d;
}

// ---------------------------------------------------------------------------
// split-bf16 MFMA GEMM: C[M,N] = A[M,K] @ B[K,N], B passed as B^T ([N][K]).
// Row-major XOR-swizzled LDS; fp32 (C) and/or bf16 (Cbf) outputs, each optional.
// 2-phase prefetch (double-buffered LDS), one vmcnt(0)+barrier pair per K-tile.
// Tiling: node GEMMs <64,128> (48KB LDS -> 3 blocks/CU); H GEMM <64,64>
//   (32KB LDS -> 5 blocks/CU = 20 waves, the TLP that hides the per-iter
//   drain; R3/R4 showed schedule depth alone does NOT move MfmaUtil at
//   2 blocks/CU — occupancy is the lever).
// SWZ=1: XCD-aware remap for the H GEMM's (32,128) grid — XCD k owns 16
//   consecutive col-tiles; per-XCD footprint A 2MB + B 1MB = L2-resident.
// Blocks with blockIdx.x >= mTiles run the fused dinv computation instead.
template <int BM, int BN, int SWZ>
__global__ __launch_bounds__(256) void gemm_mfma(
        const unsigned short* __restrict__ Ahi, const unsigned short* __restrict__ Alo,
        const unsigned short* __restrict__ BThi, const unsigned short* __restrict__ BTlo,
        float* __restrict__ C, unsigned short* __restrict__ Cbf,
        int M, int K, int N, int mTiles,
        const int* __restrict__ cur_d, const int* __restrict__ cur_p,
        float* __restrict__ dinv) {
    if ((int)blockIdx.x >= mTiles) {
        int i = (((int)blockIdx.x - mTiles) * (int)gridDim.y + (int)blockIdx.y) * 256
                + (int)threadIdx.x;
        if (i < N_NODES) {
            int deg = (i < NUM_DRUGS) ? cur_d[i * STRD] : cur_p[i * STRP];
            dinv[i] = rsqrtf((float)(deg + 1));
        }
        return;
    }
    constexpr int MI = BM / 32;           // acc row-frags per wave
    constexpr int NJ = BN / 32;           // acc col-frags per wave
    __shared__ unsigned short sAh[2][BM * 32], sAl[2][BM * 32];
    __shared__ unsigned short sBh[2][BN * 32], sBl[2][BN * 32];
    int t = threadIdx.x;
    int wv = t >> 6, lane = t & 63, quad = lane >> 4, l15 = lane & 15;
    int bx = blockIdx.x, by = blockIdx.y;
    if constexpr (SWZ) {
        // H-GEMM grid (32,128): linear id -> XCD k owns col-tiles [16k,16k+16)
        int w = by * 32 + bx;
        int xcd = w & 7, j = w >> 3;
        bx = j & 31;
        by = xcd * 16 + (j >> 5);
    }
    int m0 = bx * BM, n0 = by * BN;
    int m0w = (wv >> 1) * (BM / 2), n0w = (wv & 1) * (BN / 2);
    floatx4 zero = {0.f, 0.f, 0.f, 0.f};
    floatx4 acc[MI][NJ];
#pragma unroll
    for (int i = 0; i < MI; i++)
#pragma unroll
        for (int j = 0; j < NJ; j++) acc[i][j] = zero;

    auto STAGE = [&](int buf, int kk) {
#pragma unroll
        for (int s = t; s < BM * 4; s += 256) {   // A slots
            int row = s >> 2, pos = s & 3;
            int ch = pos ^ ((row >> 1) & 3);      // XOR-swizzled chunk
            int arow = m0 + row; if (arow > M - 1) arow = M - 1;
            size_t aoff = (size_t)arow * K + kk + ch * 8;
            gload16(Ahi + aoff, &sAh[buf][s * 8]);
            gload16(Alo + aoff, &sAl[buf][s * 8]);
        }
#pragma unroll
        for (int s = t; s < BN * 4; s += 256) {   // B slots
            int row = s >> 2, pos = s & 3;
            int ch = pos ^ ((row >> 1) & 3);
            int brow = n0 + row; if (brow > N - 1) brow = N - 1;
            size_t boff = (size_t)brow * K + kk + ch * 8;
            gload16(BThi + boff, &sBh[buf][s * 8]);
            gload16(BTlo + boff, &sBl[buf][s * 8]);
        }
    };

    int nk = K >> 5;
    STAGE(0, 0);
    asm volatile("s_waitcnt vmcnt(0)" ::: "memory");
    __builtin_amdgcn_s_barrier();
    int cur = 0;
    for (int it = 0; it < nk; ++it) {
        if (it + 1 < nk) STAGE(cur ^ 1, (it + 1) << 5);   // prefetch next tile
        short8 ah[MI], al[MI], bh[NJ], bl[NJ];
        int posq = quad ^ ((l15 >> 1) & 3);
#pragma unroll
        for (int i = 0; i < MI; i++) {
            int sl = (m0w + i * 16 + l15) * 4 + posq;
            ah[i] = *(const short8*)&sAh[cur][sl * 8];
            al[i] = *(const short8*)&sAl[cur][sl * 8];
        }
#pragma unroll
        for (int j = 0; j < NJ; j++) {
            int sl = (n0w + j * 16 + l15) * 4 + posq;
            bh[j] = *(const short8*)&sBh[cur][sl * 8];
            bl[j] = *(const short8*)&sBl[cur][sl * 8];
        }
#pragma unroll
        for (int i = 0; i < MI; i++)
#pragma unroll
            for (int j = 0; j < NJ; j++) {
                acc[i][j] = __builtin_amdgcn_mfma_f32_16x16x32_bf16(ah[i], bh[j], acc[i][j], 0, 0, 0);
                acc[i][j] = __builtin_amdgcn_mfma_f32_16x16x32_bf16(ah[i], bl[j], acc[i][j], 0, 0, 0);
                acc[i][j] = __builtin_amdgcn_mfma_f32_16x16x32_bf16(al[i], bh[j], acc[i][j], 0, 0, 0);
            }
        if (it + 1 < nk) {
            asm volatile("s_waitcnt vmcnt(0)" ::: "memory");  // next tile landed
            __builtin_amdgcn_s_barrier();                     // all reads of cur done
            cur ^= 1;
        }
    }
#pragma unroll
    for (int i = 0; i < MI; i++) {
        int gr = m0 + m0w + i * 16 + quad * 4;
#pragma unroll
        for (int r = 0; r < 4; r++) {
            if (gr + r < M) {
#pragma unroll
                for (int j = 0; j < NJ; j++) {
                    size_t o = (size_t)(gr + r) * N + n0 + n0w + j * 16 + l15;
                    float v = acc[i][j][r];
                    if (C) C[o] = v;
                    if (Cbf) Cbf[o] = f2bf(v);
                }
            }
        }
    }
}

// ---------------------------------------------------------------------------
// Layer-1 GCN aggregate. Drug destinations: one BLOCK per drug (4 waves split
// the ~98-neighbor list stride-4, LDS combine). Protein destinations: one wave
// each (deg ~11), 4/block.
__global__ __launch_bounds__(256) void aggregate1(const float* __restrict__ tmp,
                                                  const unsigned short* __restrict__ tmpbf,
                                                  const int* __restrict__ cur_d,
                                                  const int* __restrict__ adj_drug,
                                                  const int* __restrict__ cur_p,
                                                  const int* __restrict__ adj_prot,
                                                  const float* __restrict__ dinv,
                                                  const float* __restrict__ bias,
                                                  unsigned short* __restrict__ outhi,
                                                  unsigned short* __restrict__ outlo) {
    __shared__ float4 red[4][64];
    int b = blockIdx.x;
    int lane = threadIdx.x & 63;
    if (b < NB_AGG_D) {
        int d = b;
        int w = threadIdx.x >> 6;
        const int* adj = adj_drug + (size_t)d * ELLD;
        int ecnt = cur_d[d * STRD];
        int e = ecnt < ELLD ? ecnt : ELLD;
        float4 a0 = make_float4(0.f, 0.f, 0.f, 0.f);
        float4 a1 = a0, a2 = a0, a3 = a0;
        int idx = w;
        for (; idx + 12 < e; idx += 16) {
            int j0 = adj[idx], j1 = adj[idx + 4], j2 = adj[idx + 8], j3 = adj[idx + 12];
            float d0 = dinv[j0], d1 = dinv[j1], d2 = dinv[j2], d3 = dinv[j3];
            float4 v0 = bf4(&tmpbf[(size_t)j0 * CDIM + lane * 4]);
            float4 v1 = bf4(&tmpbf[(size_t)j1 * CDIM + lane * 4]);
            float4 v2 = bf4(&tmpbf[(size_t)j2 * CDIM + lane * 4]);
            float4 v3 = bf4(&tmpbf[(size_t)j3 * CDIM + lane * 4]);
            a0 = f4fma(v0, d0, a0);
            a1 = f4fma(v1, d1, a1);
            a2 = f4fma(v2, d2, a2);
            a3 = f4fma(v3, d3, a3);
        }
        for (; idx < e; idx += 4) {
            int j = adj[idx];
            a0 = f4fma(bf4(&tmpbf[(size_t)j * CDIM + lane * 4]), dinv[j], a0);
        }
        a0.x = (a0.x + a1.x) + (a2.x + a3.x);
        a0.y = (a0.y + a1.y) + (a2.y + a3.y);
        a0.z = (a0.z + a1.z) + (a2.z + a3.z);
        a0.w = (a0.w + a1.w) + (a2.w + a3.w);
        red[w][lane] = a0;
        __syncthreads();
        if (w == 0) {
            float di = dinv[d];
            float4 r0 = red[0][lane], r1 = red[1][lane], r2 = red[2][lane], r3 = red[3][lane];
            float4 self = ((const float4*)(tmp + (size_t)d * CDIM))[lane];
            float4 acc;
            acc.x = (r0.x + r1.x) + (r2.x + r3.x) + self.x * di;
            acc.y = (r0.y + r1.y) + (r2.y + r3.y) + self.y * di;
            acc.z = (r0.z + r1.z) + (r2.z + r3.z) + self.z * di;
            acc.w = (r0.w + r1.w) + (r2.w + r3.w) + self.w * di;
            float4 bv = ((const float4*)bias)[lane];
            float4 r;
            r.x = fmaxf(fmaf(acc.x, di, bv.x), 0.f);
            r.y = fmaxf(fmaf(acc.y, di, bv.y), 0.f);
            r.z = fmaxf(fmaf(acc.z, di, bv.z), 0.f);
            r.w = fmaxf(fmaf(acc.w, di, bv.w), 0.f);
            ushort4 h, l;
            split2(r.x, h.x, l.x); split2(r.y, h.y, l.y);
            split2(r.z, h.z, l.z); split2(r.w, h.w, l.w);
            *(ushort4*)&outhi[(size_t)d * CDIM + lane * 4] = h;
            *(ushort4*)&outlo[(size_t)d * CDIM + lane * 4] = l;
        }
        return;
    }
    // protein destinations: one wave per node
    int i = NUM_DRUGS + (b - NB_AGG_D) * 4 + (threadIdx.x >> 6);
    if (i >= N_NODES) return;
    float di = dinv[i];
    float4 a0 = make_float4(0.f, 0.f, 0.f, 0.f);
    float4 a1 = a0, a2 = a0, a3 = a0;
    const int* adj = adj_prot + (size_t)i * ELLP;
    int e = cur_p[i * STRP];
    int idx = 0;
    for (; idx + 4 <= e; idx += 4) {
        int j0 = adj[idx + 0], j1 = adj[idx + 1];
        int j2 = adj[idx + 2], j3 = adj[idx + 3];
        float d0 = dinv[j0], d1 = dinv[j1], d2 = dinv[j2], d3 = dinv[j3];
        float4 v0 = ((const float4*)(tmp + (size_t)j0 * CDIM))[lane];
        float4 v1 = ((const float4*)(tmp + (size_t)j1 * CDIM))[lane];
        float4 v2 = ((const float4*)(tmp + (size_t)j2 * CDIM))[lane];
        float4 v3 = ((const float4*)(tmp + (size_t)j3 * CDIM))[lane];
        a0 = f4fma(v0, d0, a0);
        a1 = f4fma(v1, d1, a1);
        a2 = f4fma(v2, d2, a2);
        a3 = f4fma(v3, d3, a3);
    }
    for (; idx < e; idx++) {
        int j = adj[idx];
        a0 = f4fma(((const float4*)(tmp + (size_t)j * CDIM))[lane], dinv[j], a0);
    }
    float4 self = ((const float4*)(tmp + (size_t)i * CDIM))[lane];
    float4 acc;
    acc.x = (a0.x + a1.x) + (a2.x + a3.x) + self.x * di;
    acc.y = (a0.y + a1.y) + (a2.y + a3.y) + self.y * di;
    acc.z = (a0.z + a1.z) + (a2.z + a3.z) + self.z * di;
    acc.w = (a0.w + a1.w) + (a2.w + a3.w) + self.w * di;
    float4 bv = ((const float4*)bias)[lane];
    float4 r;
    r.x = fmaxf(fmaf(acc.x, di, bv.x), 0.f);
    r.y = fmaxf(fmaf(acc.y, di, bv.y), 0.f);
    r.z = fmaxf(fmaf(acc.z, di, bv.z), 0.f);
    r.w = fmaxf(fmaf(acc.w, di, bv.w), 0.f);
    ushort4 h, l;
    split2(r.x, h.x, l.x); split2(r.y, h.y, l.y);
    split2(r.z, h.z, l.z); split2(r.w, h.w, l.w);
    *(ushort4*)&outhi[(size_t)i * CDIM + lane * 4] = h;
    *(ushort4*)&outlo[(size_t)i * CDIM + lane * 4] = l;
}

// Layer-2 GCN aggregate, PROTEIN rows only (drug h2 rows are dead).
__global__ __launch_bounds__(256) void aggregate2p(const float* __restrict__ tmp2,
                                                   const int* __restrict__ cur_p,
                                                   const int* __restrict__ adj_prot,
                                                   const float* __restrict__ dinv,
                                                   const float* __restrict__ bias,
                                                   unsigned short* __restrict__ h2bf) {
    int w = (blockIdx.x * blockDim.x + threadIdx.x) >> 6;
    int lane = threadIdx.x & 63;
    if (w >= N_PROT) return;
    int i = NUM_DRUGS + w;
    float di = dinv[i];
    float4 a0 = make_float4(0.f, 0.f, 0.f, 0.f);
    float4 a1 = a0, a2 = a0, a3 = a0;
    const int* adj = adj_prot + (size_t)i * ELLP;
    int e = cur_p[i * STRP];
    int idx = 0;
    for (; idx + 4 <= e; idx += 4) {
        int j0 = adj[idx + 0], j1 = adj[idx + 1];
        int j2 = adj[idx + 2], j3 = adj[idx + 3];
        float d0 = dinv[j0], d1 = dinv[j1], d2 = dinv[j2], d3 = dinv[j3];
        float4 v0 = ((const float4*)(tmp2 + (size_t)j0 * CDIM))[lane];
        float4 v1 = ((const float4*)(tmp2 + (size_t)j1 * CDIM))[lane];
        float4 v2 = ((const float4*)(tmp2 + (size_t)j2 * CDIM))[lane];
        float4 v3 = ((const float4*)(tmp2 + (size_t)j3 * CDIM))[lane];
        a0 = f4fma(v0, d0, a0);
        a1 = f4fma(v1, d1, a1);
        a2 = f4fma(v2, d2, a2);
        a3 = f4fma(v3, d3, a3);
    }
    for (; idx < e; idx++) {
        int j = adj[idx];
        a0 = f4fma(((const float4*)(tmp2 + (size_t)j * CDIM))[lane], dinv[j], a0);
    }
    float4 self = ((const float4*)(tmp2 + (size_t)i * CDIM))[lane];
    float4 acc;
    acc.x = (a0.x + a1.x) + (a2.x + a3.x) + self.x * di;
    acc.y = (a0.y + a1.y) + (a2.y + a3.y) + self.y * di;
    acc.z = (a0.z + a1.z) + (a2.z + a3.z) + self.z * di;
    acc.w = (a0.w + a1.w) + (a2.w + a3.w) + self.w * di;
    float4 bv = ((const float4*)bias)[lane];
    ushort4 o;
    o.x = f2bf(fmaxf(fmaf(acc.x, di, bv.x), 0.f));
    o.y = f2bf(fmaxf(fmaf(acc.y, di, bv.y), 0.f));
    o.z = f2bf(fmaxf(fmaf(acc.z, di, bv.z), 0.f));
    o.w = f2bf(fmaxf(fmaf(acc.w, di, bv.w), 0.f));
    *(ushort4*)&h2bf[(size_t)i * CDIM + lane * 4] = o;
}

// scatter-mean pool from bf16 h2 -> split-bf16 graph embeddings.
// One BLOCK per drug: 4 waves split the neighbor list (stride 4), LDS combine.
__global__ __launch_bounds__(256) void pool_drugs(const unsigned short* __restrict__ h2bf,
                                                  unsigned short* __restrict__ Ghi,
                                                  unsigned short* __restrict__ Glo,
                                                  const int* __restrict__ cur_d,
                                                  const int* __restrict__ adj_drug) {
    __shared__ float4 red[4][64];
    int d = blockIdx.x;
    int w = threadIdx.x >> 6, lane = threadIdx.x & 63;
    const int* adj = adj_drug + (size_t)d * ELLD;
    int ecnt = cur_d[d * STRD];
    int e = ecnt < ELLD ? ecnt : ELLD;
    float4 a0 = make_float4(0.f, 0.f, 0.f, 0.f);
    float4 a1 = a0, a2 = a0, a3 = a0;
    int idx = w;
    for (; idx + 12 < e; idx += 16) {
        int j0 = adj[idx], j1 = adj[idx + 4], j2 = adj[idx + 8], j3 = adj[idx + 12];
        float4 v0 = bf4(&h2bf[(size_t)j0 * CDIM + lane * 4]);
        float4 v1 = bf4(&h2bf[(size_t)j1 * CDIM + lane * 4]);
        float4 v2 = bf4(&h2bf[(size_t)j2 * CDIM + lane * 4]);
        float4 v3 = bf4(&h2bf[(size_t)j3 * CDIM + lane * 4]);
        a0.x += v0.x; a0.y += v0.y; a0.z += v0.z; a0.w += v0.w;
        a1.x += v1.x; a1.y += v1.y; a1.z += v1.z; a1.w += v1.w;
        a2.x += v2.x; a2.y += v2.y; a2.z += v2.z; a2.w += v2.w;
        a3.x += v3.x; a3.y += v3.y; a3.z += v3.z; a3.w += v3.w;
    }
    for (; idx < e; idx += 4) {
        float4 v = bf4(&h2bf[(size_t)adj[idx] * CDIM + lane * 4]);
        a0.x += v.x; a0.y += v.y; a0.z += v.z; a0.w += v.w;
    }
    a0.x = (a0.x + a1.x) + (a2.x + a3.x);
    a0.y = (a0.y + a1.y) + (a2.y + a3.y);
    a0.z = (a0.z + a1.z) + (a2.z + a3.z);
    a0.w = (a0.w + a1.w) + (a2.w + a3.w);
    red[w][lane] = a0;
    __syncthreads();
    if (w == 0) {
        float4 r0 = red[0][lane], r1 = red[1][lane], r2 = red[2][lane], r3 = red[3][lane];
        float4 acc;
        acc.x = (r0.x + r1.x) + (r2.x + r3.x);
        acc.y = (r0.y + r1.y) + (r2.y + r3.y);
        acc.z = (r0.z + r1.z) + (r2.z + r3.z);
        acc.w = (r0.w + r1.w) + (r2.w + r3.w);
        float sc = 1.f / (float)(ecnt > 1 ? ecnt : 1);
        acc.x *= sc; acc.y *= sc; acc.z *= sc; acc.w *= sc;
        ushort4 h, l;
        split2(acc.x, h.x, l.x); split2(acc.y, h.y, l.y);
        split2(acc.z, h.z, l.z); split2(acc.w, h.w, l.w);
        *(ushort4*)&Ghi[(size_t)d * CDIM + lane * 4] = h;
        *(ushort4*)&Glo[(size_t)d * CDIM + lane * 4] = l;
    }
}

// ---------------------------------------------------------------------------
// MLP epilogue: out[r] = sum_n relu(H[d0][2c*512+n] + H[d1][(2c+1)*512+n]
//                                   + b1[c][n]) * W2[c][n] + b2[c]
// H in bf16; one wave per row; lane covers 8 cols -> single pass, 16B loads.
__global__ __launch_bounds__(256) void mlp_out(const unsigned short* __restrict__ Hbf,
                                               const int* __restrict__ ddb,
                                               const int* __restrict__ ecl,
                                               const float* __restrict__ b1,
                                               const float* __restrict__ W2,
                                               const float* __restrict__ b2,
                                               float* __restrict__ outp) {
    int r = (blockIdx.x * blockDim.x + threadIdx.x) >> 6;
    int lane = threadIdx.x & 63;
    if (r >= BATCH) return;
    int c = ecl[r];
    int d0 = ddb[r], d1 = ddb[BATCH + r];
    int n = lane * 8;
    const unsigned short* h0 = Hbf + (size_t)d0 * HN + (size_t)(c * 2) * HID + n;
    const unsigned short* h1 = Hbf + (size_t)d1 * HN + (size_t)(c * 2 + 1) * HID + n;
    const float* b1e = b1 + (size_t)c * HID + n;
    const float* w2e = W2 + (size_t)c * HID + n;
    short8 a8 = *(const short8*)h0;
    short8 b8 = *(const short8*)h1;
    float4 bb0 = *(const float4*)(b1e);
    float4 bb1 = *(const float4*)(b1e + 4);
    float4 w0 = *(const float4*)(w2e);
    float4 w1 = *(const float4*)(w2e + 4);
    float s = 0.f;
    float h;
    h = bf2f((unsigned short)a8[0]) + bf2f((unsigned short)b8[0]) + bb0.x;
    s = fmaf(fmaxf(h, 0.f), w0.x, s);
    h = bf2f((unsigned short)a8[1]) + bf2f((unsigned short)b8[1]) + bb0.y;
    s = fmaf(fmaxf(h, 0.f), w0.y, s);
    h = bf2f((unsigned short)a8[2]) + bf2f((unsigned short)b8[2]) + bb0.z;
    s = fmaf(fmaxf(h, 0.f), w0.z, s);
    h = bf2f((unsigned short)a8[3]) + bf2f((unsigned short)b8[3]) + bb0.w;
    s = fmaf(fmaxf(h, 0.f), w0.w, s);
    h = bf2f((unsigned short)a8[4]) + bf2f((unsigned short)b8[4]) + bb1.x;
    s = fmaf(fmaxf(h, 0.f), w1.x, s);
    h = bf2f((unsigned short)a8[5]) + bf2f((unsigned short)b8[5]) + bb1.y;
    s = fmaf(fmaxf(h, 0.f), w1.y, s);
    h = bf2f((unsigned short)a8[6]) + bf2f((unsigned short)b8[6]) + bb1.z;
    s = fmaf(fmaxf(h, 0.f), w1.z, s);
    h = bf2f((unsigned short)a8[7]) + bf2f((unsigned short)b8[7]) + bb1.w;
    s = fmaf(fmaxf(h, 0.f), w1.w, s);
    s += __shfl_xor(s, 1);
    s += __shfl_xor(s, 2);
    s += __shfl_xor(s, 4);
    s += __shfl_xor(s, 8);
    s += __shfl_xor(s, 16);
    s += __shfl_xor(s, 32);
    if (lane == 0) outp[r] = s + b2[c];
}

// ---------------------------------------------------------------------------
extern "C" void kernel_launch(void* const* d_in, const int* in_sizes, int n_in,
                              void* d_out, int out_size, void* d_ws, size_t ws_size,
                              hipStream_t stream) {
    const float* x   = (const float*)d_in[0];
    const int* ei    = (const int*)d_in[1];
    const int* ddb   = (const int*)d_in[2];
    const int* ecl   = (const int*)d_in[3];
    const float* Wg1 = (const float*)d_in[5];
    const float* bg1 = (const float*)d_in[6];
    const float* Wg2 = (const float*)d_in[7];
    const float* bg2 = (const float*)d_in[8];
    const float* W1  = (const float*)d_in[9];
    const float* b1  = (const float*)d_in[10];
    const float* W2  = (const float*)d_in[11];
    const float* b2  = (const float*)d_in[12];
    float* outp = (float*)d_out;

    const size_t NC = (size_t)N_NODES * CDIM;                      // 5.12M elems
    const size_t HRES = (size_t)NUM_DRUGS * HN * sizeof(float);    // 67.1 MB reserved
    // Region 0 (inside reserved extent; all dead before the H GEMM writes Hbf):
    // Hbf (bf16, 33.6 MB) overlaps tmp/t1bf/h1 — all dead at H-GEMM time.
    char* r0 = (char*)d_ws;
    unsigned short* Hbf   = (unsigned short*)d_ws;
    float* tmp            = (float*)r0;
    unsigned short* t1bf  = (unsigned short*)(r0 + 20480000);
    unsigned short* h2bf  = t1bf;
    unsigned short* h1hi  = (unsigned short*)(r0 + 30720000);
    unsigned short* h1lo  = (unsigned short*)(r0 + 40960000);
    unsigned short* xhi   = h1hi;
    unsigned short* xlo   = h1lo;
    char* p = r0 + 51200000;
    auto alloc = [&](size_t bytes) {
        char* r = p;
        p += (bytes + 255) & ~size_t(255);
        return (void*)r;
    };
    float* dinv    = (float*)alloc(sizeof(float) * N_NODES);
    int* cur_d     = (int*)alloc(sizeof(int) * NUM_DRUGS * STRD);
    int* cur_p     = (int*)alloc(sizeof(int) * N_NODES * STRP);
    int* adj_drug  = (int*)alloc(sizeof(int) * NUM_DRUGS * ELLD);
    int* adj_prot  = (int*)alloc(sizeof(int) * (size_t)N_NODES * ELLP);
    // Region 1 (after reserved extent): buffers the H GEMM reads
    p = (char*)d_ws + ((HRES + 255) & ~size_t(255));
    unsigned short* Ghi   = (unsigned short*)alloc(2 * NUM_DRUGS * CDIM);
    unsigned short* Glo   = (unsigned short*)alloc(2 * NUM_DRUGS * CDIM);
    unsigned short* wg1Th = (unsigned short*)alloc(2 * CDIM * CDIM);
    unsigned short* wg1Tl = (unsigned short*)alloc(2 * CDIM * CDIM);
    unsigned short* wg2Th = (unsigned short*)alloc(2 * CDIM * CDIM);
    unsigned short* wg2Tl = (unsigned short*)alloc(2 * CDIM * CDIM);
    unsigned short* W1Th  = (unsigned short*)alloc(2 * (size_t)N_CL * HID * HID);
    unsigned short* W1Tl  = (unsigned short*)alloc(2 * (size_t)N_CL * HID * HID);

    // fused prep: counter zero + x split + Wg transposes + W1 transpose (1 dispatch)
    prep_all<<<NB_T64 + NB_TWG + NB_ZERO + NB_SPLIT, 256, 0, stream>>>(
        x, xhi, xlo, Wg1, Wg2, wg1Th, wg1Tl, wg2Th, wg2Tl, W1, W1Th, W1Tl,
        cur_d, cur_p);
    // ELL fill (needs zeroed counters)
    fill_ell<<<(NUM_DPI + 255) / 256, 256, 0, stream>>>(ei, cur_d, adj_drug,
                                                        cur_p, adj_prot);
    // GCN layer 1 (GEMM also emits bf16 copy for the drug-side gather);
    // dinv computation fused in as 80 extra blocks (blockIdx.x >= 313).
    gemm_mfma<64, 128, 0><<<dim3(MT_NODE + 40, 2), 256, 0, stream>>>(
        xhi, xlo, wg1Th, wg1Tl, tmp, t1bf, N_NODES, CDIM, CDIM,
        MT_NODE, cur_d, cur_p, dinv);
    aggregate1<<<NB_AGG_D + NB_AGG_P, 256, 0, stream>>>(
        tmp, t1bf, cur_d, adj_drug, cur_p, adj_prot, dinv, bg1, h1hi, h1lo);
    // GCN layer 2 (protein rows only downstream)
    gemm_mfma<64, 128, 0><<<dim3(MT_NODE, 2), 256, 0, stream>>>(
        h1hi, h1lo, wg2Th, wg2Tl, tmp, nullptr, N_NODES, CDIM, CDIM,
        MT_NODE, nullptr, nullptr, nullptr);
    aggregate2p<<<(N_PROT * 64 + 255) / 256, 256, 0, stream>>>(
        tmp, cur_p, adj_prot, dinv, bg2, h2bf);
    // pool (bf16 gather, 4 waves/drug) -> split graph embeddings
    pool_drugs<<<NUM_DRUGS, 256, 0, stream>>>(h2bf, Ghi, Glo, cur_d, adj_drug);
    // MLP precompute: Hbf[2048, 8192] (bf16) = G @ W1cat
    // 64x64 tiles, 32KB LDS -> 5 blocks/CU (TLP), XCD-swizzled (32,128) grid
    gemm_mfma<64, 64, 1><<<dim3(NUM_DRUGS / 64, HN / 64), 256, 0, stream>>>(
        Ghi, Glo, W1Th, W1Tl, nullptr, Hbf, NUM_DRUGS, CDIM, HN,
        NUM_DRUGS / 64, nullptr, nullptr, nullptr);
    // epilogue: gather 2 Hbf rows per batch row, relu+dot, direct store
    mlp_out<<<(BATCH * 64) / 256, 256, 0, stream>>>(Hbf, ddb, ecl, b1, W2, b2, outp);
}

// Round 6
// 255.553 us; speedup vs baseline: 1.0147x; 1.0147x over previous
//
#include <hip/hip_runtime.h>
#include <hip/hip_bf16.h>

// Problem constants (fixed by reference)
#define N_NODES 20000
#define NUM_DRUGS 2048
#define N_PROT (N_NODES - NUM_DRUGS)
#define NUM_DPI 200000
#define E2 400000          // 2*NUM_DPI directed edges
#define CDIM 256           // IN_C == EMB == 256
#define HID 512
#define N_CL 8
#define BATCH 16384
#define HN 8192            // H cols = 8 experts x 2 halves x 512

#define STRD 32            // drug counter padding (ints) = 1 line per counter
#define STRP 16            // protein counter padding
#define ELLD 192           // drug ELL stride (mean deg 97.7, +9.5 sigma)
#define ELLP 48            // protein ELL stride (mean deg 11.1, +11 sigma)

// fused-prep block ranges
#define NB_T64 512         // W1 transpose: 4 x 8 x 16
#define NB_TWG 32          // Wg1/Wg2 transpose: 4 x 4 x 2
#define NB_ZERO 79         // counter zeroing
#define NB_SPLIT 20000     // x split: 5.12M / 256

// node-GEMM tiling (BM=64): 313 row tiles
#define MT_NODE 313

// aggregate1 grid split
#define NB_AGG_D NUM_DRUGS              // 1 block per drug (4 waves)
#define NB_AGG_P ((N_PROT + 3) / 4)     // 4 proteins per block (1 wave each)

typedef __attribute__((ext_vector_type(8))) short short8;   // 8 bf16 (MFMA A/B frag)
typedef __attribute__((ext_vector_type(4))) float floatx4;  // MFMA C/D frag

__device__ inline unsigned short f2bf(float f) {
    unsigned u = __float_as_uint(f);
    u += 0x7fff + ((u >> 16) & 1);   // RNE
    return (unsigned short)(u >> 16);
}
__device__ inline float bf2f(unsigned short h) {
    return __uint_as_float((unsigned)h << 16);
}
__device__ inline void split2(float v, unsigned short& h, unsigned short& l) {
    h = f2bf(v);
    l = f2bf(v - bf2f(h));
}
__device__ inline void gload16(const void* g, void* l) {
    __builtin_amdgcn_global_load_lds(
        (const __attribute__((address_space(1))) void*)g,
        (__attribute__((address_space(3))) void*)l, 16, 0, 0);
}
__device__ inline float4 f4fma(float4 v, float s, float4 a) {
    a.x = fmaf(v.x, s, a.x); a.y = fmaf(v.y, s, a.y);
    a.z = fmaf(v.z, s, a.z); a.w = fmaf(v.w, s, a.w);
    return a;
}
__device__ inline float4 bf4(const unsigned short* p) {
    ushort4 q = *(const ushort4*)p;
    return make_float4(bf2f(q.x), bf2f(q.y), bf2f(q.z), bf2f(q.w));
}

// ---------------------------------------------------------------------------
// Fused prep: W1 transpose-split | Wg1/Wg2 transpose-split | counter zero |
// x split. All mutually independent; one dispatch instead of four.
__global__ __launch_bounds__(256) void prep_all(
        const float* __restrict__ x, unsigned short* __restrict__ xhi,
        unsigned short* __restrict__ xlo,
        const float* __restrict__ Wg1, const float* __restrict__ Wg2,
        unsigned short* __restrict__ wg1Th, unsigned short* __restrict__ wg1Tl,
        unsigned short* __restrict__ wg2Th, unsigned short* __restrict__ wg2Tl,
        const float* __restrict__ W1, unsigned short* __restrict__ W1Th,
        unsigned short* __restrict__ W1Tl,
        int* __restrict__ cur_d, int* __restrict__ cur_p) {
    __shared__ float ld[64 * 65];
    int b = blockIdx.x;
    int t = threadIdx.x;
    int tx = t & 63, ty = t >> 6;
    if (b < NB_T64) {
        // W1 [16 slabs][256][512] -> W1cat^T [8192][256] split bf16
        int m = b >> 5;
        int k0 = (b & 3) * 64, n0 = ((b >> 2) & 7) * 64;
        const float* Wm = W1 + (size_t)m * CDIM * HID;
#pragma unroll
        for (int rr = 0; rr < 16; rr++) {
            int kl = rr * 4 + ty;
            ld[tx * 65 + kl] = Wm[(size_t)(k0 + kl) * HID + n0 + tx];
        }
        __syncthreads();
        size_t obase = (size_t)m * HID * CDIM;
#pragma unroll
        for (int rr = 0; rr < 16; rr++) {
            int nl = rr * 4 + ty;
            float v = ld[nl * 65 + tx];
            unsigned short h, l;
            split2(v, h, l);
            size_t o = obase + (size_t)(n0 + nl) * CDIM + k0 + tx;
            W1Th[o] = h;
            W1Tl[o] = l;
        }
        return;
    }
    b -= NB_T64;
    if (b < NB_TWG) {
        // Wg1/Wg2 [256][256] -> transposed split bf16
        const float* W = (b >> 4) ? Wg2 : Wg1;
        unsigned short* hi = (b >> 4) ? wg2Th : wg1Th;
        unsigned short* lo = (b >> 4) ? wg2Tl : wg1Tl;
        int k0 = (b & 3) * 64, n0 = ((b >> 2) & 3) * 64;
#pragma unroll
        for (int rr = 0; rr < 16; rr++) {
            int kl = rr * 4 + ty;
            ld[tx * 65 + kl] = W[(size_t)(k0 + kl) * CDIM + n0 + tx];
        }
        __syncthreads();
#pragma unroll
        for (int rr = 0; rr < 16; rr++) {
            int nl = rr * 4 + ty;
            float v = ld[nl * 65 + tx];
            unsigned short h, l;
            split2(v, h, l);
            size_t o = (size_t)(n0 + nl) * CDIM + k0 + tx;
            hi[o] = h;
            lo[o] = l;
        }
        return;
    }
    b -= NB_TWG;
    if (b < NB_ZERO) {
        int i = b * 256 + t;
        if (i < N_NODES) cur_p[i * STRP] = 0;
        if (i < NUM_DRUGS) cur_d[i * STRD] = 0;
        return;
    }
    b -= NB_ZERO;
    {   // x split: exactly NB_SPLIT blocks cover 5.12M elems
        int i = b * 256 + t;
        unsigned short h, l;
        split2(x[i], h, l);
        xhi[i] = h;
        xlo[i] = l;
    }
}

// fill both ELL adjacency lists directly (no count/scan passes needed)
__global__ void fill_ell(const int* __restrict__ ei, int* cur_d, int* adj_drug,
                         int* cur_p, int* adj_prot) {
    int e = blockIdx.x * blockDim.x + threadIdx.x;
    if (e >= NUM_DPI) return;
    int d = ei[e];
    int p = ei[E2 + e];
    int posd = atomicAdd(&cur_d[d * STRD], 1);
    int posp = atomicAdd(&cur_p[p * STRP], 1);
    if (posd < ELLD) adj_drug[d * ELLD + posd] = p;   // clamp: never corrupt neighbor
    if (posp < ELLP) adj_prot[(size_t)p * ELLP + posp] = d;
}

// ---------------------------------------------------------------------------
// split-bf16 MFMA GEMM: C[M,N] = A[M,K] @ B[K,N], B passed as B^T ([N][K]).
// Row-major XOR-swizzled LDS; fp32 (C) and/or bf16 (Cbf) outputs, each optional.
// DBUF=1: 2-phase prefetch, double-buffered LDS (node GEMMs: 48KB, 3 blk/CU,
//   grid-limited to ~2.4/CU anyway).
// DBUF=0: single-buffered LDS (H GEMM: 128x128 = 32KB -> 5 blocks/CU = 20
//   waves). R3/R4/R5 isolated that neither pipeline depth (2 blk/CU) nor TLP
//   at low intensity (64x64) moves MfmaUtil off ~21%; this is the
//   high-intensity (48 MFMA/wave-iter) + high-TLP quadrant: 5 desynced
//   blocks/CU cross-cover the exposed stage phase, and staging traffic is
//   half of the 64x64 config (256 MB vs 512 MB L2->LDS).
// SWZ=1: XCD-aware remap for the H GEMM's (16,64) grid — XCD k owns col-tiles
//   [8k,8k+8); per-XCD footprint A 2MB + B 1MB = L2-resident. Bijective.
// Blocks with blockIdx.x >= mTiles run the fused dinv computation instead.
template <int BM, int BN, int SWZ, int DBUF>
__global__ __launch_bounds__(256) void gemm_mfma(
        const unsigned short* __restrict__ Ahi, const unsigned short* __restrict__ Alo,
        const unsigned short* __restrict__ BThi, const unsigned short* __restrict__ BTlo,
        float* __restrict__ C, unsigned short* __restrict__ Cbf,
        int M, int K, int N, int mTiles,
        const int* __restrict__ cur_d, const int* __restrict__ cur_p,
        float* __restrict__ dinv) {
    if ((int)blockIdx.x >= mTiles) {
        int i = (((int)blockIdx.x - mTiles) * (int)gridDim.y + (int)blockIdx.y) * 256
                + (int)threadIdx.x;
        if (i < N_NODES) {
            int deg = (i < NUM_DRUGS) ? cur_d[i * STRD] : cur_p[i * STRP];
            dinv[i] = rsqrtf((float)(deg + 1));
        }
        return;
    }
    constexpr int MI = BM / 32;           // acc row-frags per wave
    constexpr int NJ = BN / 32;           // acc col-frags per wave
    constexpr int NB = DBUF ? 2 : 1;      // LDS buffers
    __shared__ unsigned short sAh[NB][BM * 32], sAl[NB][BM * 32];
    __shared__ unsigned short sBh[NB][BN * 32], sBl[NB][BN * 32];
    int t = threadIdx.x;
    int wv = t >> 6, lane = t & 63, quad = lane >> 4, l15 = lane & 15;
    int bx = blockIdx.x, by = blockIdx.y;
    if constexpr (SWZ) {
        // H-GEMM grid (16,64): linear id -> XCD k owns col-tiles [8k,8k+8)
        int w = by * 16 + bx;
        int xcd = w & 7, j = w >> 3;
        bx = j & 15;
        by = xcd * 8 + (j >> 4);
    }
    int m0 = bx * BM, n0 = by * BN;
    int m0w = (wv >> 1) * (BM / 2), n0w = (wv & 1) * (BN / 2);
    floatx4 zero = {0.f, 0.f, 0.f, 0.f};
    floatx4 acc[MI][NJ];
#pragma unroll
    for (int i = 0; i < MI; i++)
#pragma unroll
        for (int j = 0; j < NJ; j++) acc[i][j] = zero;

    auto STAGE = [&](int buf, int kk) {
#pragma unroll
        for (int s = t; s < BM * 4; s += 256) {   // A slots
            int row = s >> 2, pos = s & 3;
            int ch = pos ^ ((row >> 1) & 3);      // XOR-swizzled chunk
            int arow = m0 + row; if (arow > M - 1) arow = M - 1;
            size_t aoff = (size_t)arow * K + kk + ch * 8;
            gload16(Ahi + aoff, &sAh[buf][s * 8]);
            gload16(Alo + aoff, &sAl[buf][s * 8]);
        }
#pragma unroll
        for (int s = t; s < BN * 4; s += 256) {   // B slots
            int row = s >> 2, pos = s & 3;
            int ch = pos ^ ((row >> 1) & 3);
            int brow = n0 + row; if (brow > N - 1) brow = N - 1;
            size_t boff = (size_t)brow * K + kk + ch * 8;
            gload16(BThi + boff, &sBh[buf][s * 8]);
            gload16(BTlo + boff, &sBl[buf][s * 8]);
        }
    };

    auto COMPUTE = [&](int cur) {
        short8 ah[MI], al[MI], bh[NJ], bl[NJ];
        int posq = quad ^ ((l15 >> 1) & 3);
#pragma unroll
        for (int i = 0; i < MI; i++) {
            int sl = (m0w + i * 16 + l15) * 4 + posq;
            ah[i] = *(const short8*)&sAh[cur][sl * 8];
            al[i] = *(const short8*)&sAl[cur][sl * 8];
        }
#pragma unroll
        for (int j = 0; j < NJ; j++) {
            int sl = (n0w + j * 16 + l15) * 4 + posq;
            bh[j] = *(const short8*)&sBh[cur][sl * 8];
            bl[j] = *(const short8*)&sBl[cur][sl * 8];
        }
#pragma unroll
        for (int i = 0; i < MI; i++)
#pragma unroll
            for (int j = 0; j < NJ; j++) {
                acc[i][j] = __builtin_amdgcn_mfma_f32_16x16x32_bf16(ah[i], bh[j], acc[i][j], 0, 0, 0);
                acc[i][j] = __builtin_amdgcn_mfma_f32_16x16x32_bf16(ah[i], bl[j], acc[i][j], 0, 0, 0);
                acc[i][j] = __builtin_amdgcn_mfma_f32_16x16x32_bf16(al[i], bh[j], acc[i][j], 0, 0, 0);
            }
    };

    int nk = K >> 5;
    if constexpr (DBUF) {
        STAGE(0, 0);
        asm volatile("s_waitcnt vmcnt(0)" ::: "memory");
        __builtin_amdgcn_s_barrier();
        int cur = 0;
        for (int it = 0; it < nk; ++it) {
            if (it + 1 < nk) STAGE(cur ^ 1, (it + 1) << 5);   // prefetch next
            COMPUTE(cur);
            if (it + 1 < nk) {
                asm volatile("s_waitcnt vmcnt(0)" ::: "memory");
                __builtin_amdgcn_s_barrier();
                cur ^= 1;
            }
        }
    } else {
        for (int it = 0; it < nk; ++it) {
            STAGE(0, it << 5);
            asm volatile("s_waitcnt vmcnt(0)" ::: "memory");
            __builtin_amdgcn_s_barrier();
            COMPUTE(0);
            if (it + 1 < nk) __builtin_amdgcn_s_barrier();  // LDS reuse guard
        }
    }
#pragma unroll
    for (int i = 0; i < MI; i++) {
        int gr = m0 + m0w + i * 16 + quad * 4;
#pragma unroll
        for (int r = 0; r < 4; r++) {
            if (gr + r < M) {
#pragma unroll
                for (int j = 0; j < NJ; j++) {
                    size_t o = (size_t)(gr + r) * N + n0 + n0w + j * 16 + l15;
                    float v = acc[i][j][r];
                    if (C) C[o] = v;
                    if (Cbf) Cbf[o] = f2bf(v);
                }
            }
        }
    }
}

// ---------------------------------------------------------------------------
// Layer-1 GCN aggregate. Drug destinations: one BLOCK per drug (4 waves split
// the ~98-neighbor list stride-4, LDS combine). Protein destinations: one wave
// each (deg ~11), 4/block.
__global__ __launch_bounds__(256) void aggregate1(const float* __restrict__ tmp,
                                                  const unsigned short* __restrict__ tmpbf,
                                                  const int* __restrict__ cur_d,
                                                  const int* __restrict__ adj_drug,
                                                  const int* __restrict__ cur_p,
                                                  const int* __restrict__ adj_prot,
                                                  const float* __restrict__ dinv,
                                                  const float* __restrict__ bias,
                                                  unsigned short* __restrict__ outhi,
                                                  unsigned short* __restrict__ outlo) {
    __shared__ float4 red[4][64];
    int b = blockIdx.x;
    int lane = threadIdx.x & 63;
    if (b < NB_AGG_D) {
        int d = b;
        int w = threadIdx.x >> 6;
        const int* adj = adj_drug + (size_t)d * ELLD;
        int ecnt = cur_d[d * STRD];
        int e = ecnt < ELLD ? ecnt : ELLD;
        float4 a0 = make_float4(0.f, 0.f, 0.f, 0.f);
        float4 a1 = a0, a2 = a0, a3 = a0;
        int idx = w;
        for (; idx + 12 < e; idx += 16) {
            int j0 = adj[idx], j1 = adj[idx + 4], j2 = adj[idx + 8], j3 = adj[idx + 12];
            float d0 = dinv[j0], d1 = dinv[j1], d2 = dinv[j2], d3 = dinv[j3];
            float4 v0 = bf4(&tmpbf[(size_t)j0 * CDIM + lane * 4]);
            float4 v1 = bf4(&tmpbf[(size_t)j1 * CDIM + lane * 4]);
            float4 v2 = bf4(&tmpbf[(size_t)j2 * CDIM + lane * 4]);
            float4 v3 = bf4(&tmpbf[(size_t)j3 * CDIM + lane * 4]);
            a0 = f4fma(v0, d0, a0);
            a1 = f4fma(v1, d1, a1);
            a2 = f4fma(v2, d2, a2);
            a3 = f4fma(v3, d3, a3);
        }
        for (; idx < e; idx += 4) {
            int j = adj[idx];
            a0 = f4fma(bf4(&tmpbf[(size_t)j * CDIM + lane * 4]), dinv[j], a0);
        }
        a0.x = (a0.x + a1.x) + (a2.x + a3.x);
        a0.y = (a0.y + a1.y) + (a2.y + a3.y);
        a0.z = (a0.z + a1.z) + (a2.z + a3.z);
        a0.w = (a0.w + a1.w) + (a2.w + a3.w);
        red[w][lane] = a0;
        __syncthreads();
        if (w == 0) {
            float di = dinv[d];
            float4 r0 = red[0][lane], r1 = red[1][lane], r2 = red[2][lane], r3 = red[3][lane];
            float4 self = ((const float4*)(tmp + (size_t)d * CDIM))[lane];
            float4 acc;
            acc.x = (r0.x + r1.x) + (r2.x + r3.x) + self.x * di;
            acc.y = (r0.y + r1.y) + (r2.y + r3.y) + self.y * di;
            acc.z = (r0.z + r1.z) + (r2.z + r3.z) + self.z * di;
            acc.w = (r0.w + r1.w) + (r2.w + r3.w) + self.w * di;
            float4 bv = ((const float4*)bias)[lane];
            float4 r;
            r.x = fmaxf(fmaf(acc.x, di, bv.x), 0.f);
            r.y = fmaxf(fmaf(acc.y, di, bv.y), 0.f);
            r.z = fmaxf(fmaf(acc.z, di, bv.z), 0.f);
            r.w = fmaxf(fmaf(acc.w, di, bv.w), 0.f);
            ushort4 h, l;
            split2(r.x, h.x, l.x); split2(r.y, h.y, l.y);
            split2(r.z, h.z, l.z); split2(r.w, h.w, l.w);
            *(ushort4*)&outhi[(size_t)d * CDIM + lane * 4] = h;
            *(ushort4*)&outlo[(size_t)d * CDIM + lane * 4] = l;
        }
        return;
    }
    // protein destinations: one wave per node
    int i = NUM_DRUGS + (b - NB_AGG_D) * 4 + (threadIdx.x >> 6);
    if (i >= N_NODES) return;
    float di = dinv[i];
    float4 a0 = make_float4(0.f, 0.f, 0.f, 0.f);
    float4 a1 = a0, a2 = a0, a3 = a0;
    const int* adj = adj_prot + (size_t)i * ELLP;
    int e = cur_p[i * STRP];
    int idx = 0;
    for (; idx + 4 <= e; idx += 4) {
        int j0 = adj[idx + 0], j1 = adj[idx + 1];
        int j2 = adj[idx + 2], j3 = adj[idx + 3];
        float d0 = dinv[j0], d1 = dinv[j1], d2 = dinv[j2], d3 = dinv[j3];
        float4 v0 = ((const float4*)(tmp + (size_t)j0 * CDIM))[lane];
        float4 v1 = ((const float4*)(tmp + (size_t)j1 * CDIM))[lane];
        float4 v2 = ((const float4*)(tmp + (size_t)j2 * CDIM))[lane];
        float4 v3 = ((const float4*)(tmp + (size_t)j3 * CDIM))[lane];
        a0 = f4fma(v0, d0, a0);
        a1 = f4fma(v1, d1, a1);
        a2 = f4fma(v2, d2, a2);
        a3 = f4fma(v3, d3, a3);
    }
    for (; idx < e; idx++) {
        int j = adj[idx];
        a0 = f4fma(((const float4*)(tmp + (size_t)j * CDIM))[lane], dinv[j], a0);
    }
    float4 self = ((const float4*)(tmp + (size_t)i * CDIM))[lane];
    float4 acc;
    acc.x = (a0.x + a1.x) + (a2.x + a3.x) + self.x * di;
    acc.y = (a0.y + a1.y) + (a2.y + a3.y) + self.y * di;
    acc.z = (a0.z + a1.z) + (a2.z + a3.z) + self.z * di;
    acc.w = (a0.w + a1.w) + (a2.w + a3.w) + self.w * di;
    float4 bv = ((const float4*)bias)[lane];
    float4 r;
    r.x = fmaxf(fmaf(acc.x, di, bv.x), 0.f);
    r.y = fmaxf(fmaf(acc.y, di, bv.y), 0.f);
    r.z = fmaxf(fmaf(acc.z, di, bv.z), 0.f);
    r.w = fmaxf(fmaf(acc.w, di, bv.w), 0.f);
    ushort4 h, l;
    split2(r.x, h.x, l.x); split2(r.y, h.y, l.y);
    split2(r.z, h.z, l.z); split2(r.w, h.w, l.w);
    *(ushort4*)&outhi[(size_t)i * CDIM + lane * 4] = h;
    *(ushort4*)&outlo[(size_t)i * CDIM + lane * 4] = l;
}

// Layer-2 GCN aggregate, PROTEIN rows only (drug h2 rows are dead).
__global__ __launch_bounds__(256) void aggregate2p(const float* __restrict__ tmp2,
                                                   const int* __restrict__ cur_p,
                                                   const int* __restrict__ adj_prot,
                                                   const float* __restrict__ dinv,
                                                   const float* __restrict__ bias,
                                                   unsigned short* __restrict__ h2bf) {
    int w = (blockIdx.x * blockDim.x + threadIdx.x) >> 6;
    int lane = threadIdx.x & 63;
    if (w >= N_PROT) return;
    int i = NUM_DRUGS + w;
    float di = dinv[i];
    float4 a0 = make_float4(0.f, 0.f, 0.f, 0.f);
    float4 a1 = a0, a2 = a0, a3 = a0;
    const int* adj = adj_prot + (size_t)i * ELLP;
    int e = cur_p[i * STRP];
    int idx = 0;
    for (; idx + 4 <= e; idx += 4) {
        int j0 = adj[idx + 0], j1 = adj[idx + 1];
        int j2 = adj[idx + 2], j3 = adj[idx + 3];
        float d0 = dinv[j0], d1 = dinv[j1], d2 = dinv[j2], d3 = dinv[j3];
        float4 v0 = ((const float4*)(tmp2 + (size_t)j0 * CDIM))[lane];
        float4 v1 = ((const float4*)(tmp2 + (size_t)j1 * CDIM))[lane];
        float4 v2 = ((const float4*)(tmp2 + (size_t)j2 * CDIM))[lane];
        float4 v3 = ((const float4*)(tmp2 + (size_t)j3 * CDIM))[lane];
        a0 = f4fma(v0, d0, a0);
        a1 = f4fma(v1, d1, a1);
        a2 = f4fma(v2, d2, a2);
        a3 = f4fma(v3, d3, a3);
    }
    for (; idx < e; idx++) {
        int j = adj[idx];
        a0 = f4fma(((const float4*)(tmp2 + (size_t)j * CDIM))[lane], dinv[j], a0);
    }
    float4 self = ((const float4*)(tmp2 + (size_t)i * CDIM))[lane];
    float4 acc;
    acc.x = (a0.x + a1.x) + (a2.x + a3.x) + self.x * di;
    acc.y = (a0.y + a1.y) + (a2.y + a3.y) + self.y * di;
    acc.z = (a0.z + a1.z) + (a2.z + a3.z) + self.z * di;
    acc.w = (a0.w + a1.w) + (a2.w + a3.w) + self.w * di;
    float4 bv = ((const float4*)bias)[lane];
    ushort4 o;
    o.x = f2bf(fmaxf(fmaf(acc.x, di, bv.x), 0.f));
    o.y = f2bf(fmaxf(fmaf(acc.y, di, bv.y), 0.f));
    o.z = f2bf(fmaxf(fmaf(acc.z, di, bv.z), 0.f));
    o.w = f2bf(fmaxf(fmaf(acc.w, di, bv.w), 0.f));
    *(ushort4*)&h2bf[(size_t)i * CDIM + lane * 4] = o;
}

// scatter-mean pool from bf16 h2 -> split-bf16 graph embeddings.
// One BLOCK per drug: 4 waves split the neighbor list (stride 4), LDS combine.
__global__ __launch_bounds__(256) void pool_drugs(const unsigned short* __restrict__ h2bf,
                                                  unsigned short* __restrict__ Ghi,
                                                  unsigned short* __restrict__ Glo,
                                                  const int* __restrict__ cur_d,
                                                  const int* __restrict__ adj_drug) {
    __shared__ float4 red[4][64];
    int d = blockIdx.x;
    int w = threadIdx.x >> 6, lane = threadIdx.x & 63;
    const int* adj = adj_drug + (size_t)d * ELLD;
    int ecnt = cur_d[d * STRD];
    int e = ecnt < ELLD ? ecnt : ELLD;
    float4 a0 = make_float4(0.f, 0.f, 0.f, 0.f);
    float4 a1 = a0, a2 = a0, a3 = a0;
    int idx = w;
    for (; idx + 12 < e; idx += 16) {
        int j0 = adj[idx], j1 = adj[idx + 4], j2 = adj[idx + 8], j3 = adj[idx + 12];
        float4 v0 = bf4(&h2bf[(size_t)j0 * CDIM + lane * 4]);
        float4 v1 = bf4(&h2bf[(size_t)j1 * CDIM + lane * 4]);
        float4 v2 = bf4(&h2bf[(size_t)j2 * CDIM + lane * 4]);
        float4 v3 = bf4(&h2bf[(size_t)j3 * CDIM + lane * 4]);
        a0.x += v0.x; a0.y += v0.y; a0.z += v0.z; a0.w += v0.w;
        a1.x += v1.x; a1.y += v1.y; a1.z += v1.z; a1.w += v1.w;
        a2.x += v2.x; a2.y += v2.y; a2.z += v2.z; a2.w += v2.w;
        a3.x += v3.x; a3.y += v3.y; a3.z += v3.z; a3.w += v3.w;
    }
    for (; idx < e; idx += 4) {
        float4 v = bf4(&h2bf[(size_t)adj[idx] * CDIM + lane * 4]);
        a0.x += v.x; a0.y += v.y; a0.z += v.z; a0.w += v.w;
    }
    a0.x = (a0.x + a1.x) + (a2.x + a3.x);
    a0.y = (a0.y + a1.y) + (a2.y + a3.y);
    a0.z = (a0.z + a1.z) + (a2.z + a3.z);
    a0.w = (a0.w + a1.w) + (a2.w + a3.w);
    red[w][lane] = a0;
    __syncthreads();
    if (w == 0) {
        float4 r0 = red[0][lane], r1 = red[1][lane], r2 = red[2][lane], r3 = red[3][lane];
        float4 acc;
        acc.x = (r0.x + r1.x) + (r2.x + r3.x);
        acc.y = (r0.y + r1.y) + (r2.y + r3.y);
        acc.z = (r0.z + r1.z) + (r2.z + r3.z);
        acc.w = (r0.w + r1.w) + (r2.w + r3.w);
        float sc = 1.f / (float)(ecnt > 1 ? ecnt : 1);
        acc.x *= sc; acc.y *= sc; acc.z *= sc; acc.w *= sc;
        ushort4 h, l;
        split2(acc.x, h.x, l.x); split2(acc.y, h.y, l.y);
        split2(acc.z, h.z, l.z); split2(acc.w, h.w, l.w);
        *(ushort4*)&Ghi[(size_t)d * CDIM + lane * 4] = h;
        *(ushort4*)&Glo[(size_t)d * CDIM + lane * 4] = l;
    }
}

// ---------------------------------------------------------------------------
// MLP epilogue: out[r] = sum_n relu(H[d0][2c*512+n] + H[d1][(2c+1)*512+n]
//                                   + b1[c][n]) * W2[c][n] + b2[c]
// H in bf16; one wave per row; lane covers 8 cols -> single pass, 16B loads.
__global__ __launch_bounds__(256) void mlp_out(const unsigned short* __restrict__ Hbf,
                                               const int* __restrict__ ddb,
                                               const int* __restrict__ ecl,
                                               const float* __restrict__ b1,
                                               const float* __restrict__ W2,
                                               const float* __restrict__ b2,
                                               float* __restrict__ outp) {
    int r = (blockIdx.x * blockDim.x + threadIdx.x) >> 6;
    int lane = threadIdx.x & 63;
    if (r >= BATCH) return;
    int c = ecl[r];
    int d0 = ddb[r], d1 = ddb[BATCH + r];
    int n = lane * 8;
    const unsigned short* h0 = Hbf + (size_t)d0 * HN + (size_t)(c * 2) * HID + n;
    const unsigned short* h1 = Hbf + (size_t)d1 * HN + (size_t)(c * 2 + 1) * HID + n;
    const float* b1e = b1 + (size_t)c * HID + n;
    const float* w2e = W2 + (size_t)c * HID + n;
    short8 a8 = *(const short8*)h0;
    short8 b8 = *(const short8*)h1;
    float4 bb0 = *(const float4*)(b1e);
    float4 bb1 = *(const float4*)(b1e + 4);
    float4 w0 = *(const float4*)(w2e);
    float4 w1 = *(const float4*)(w2e + 4);
    float s = 0.f;
    float h;
    h = bf2f((unsigned short)a8[0]) + bf2f((unsigned short)b8[0]) + bb0.x;
    s = fmaf(fmaxf(h, 0.f), w0.x, s);
    h = bf2f((unsigned short)a8[1]) + bf2f((unsigned short)b8[1]) + bb0.y;
    s = fmaf(fmaxf(h, 0.f), w0.y, s);
    h = bf2f((unsigned short)a8[2]) + bf2f((unsigned short)b8[2]) + bb0.z;
    s = fmaf(fmaxf(h, 0.f), w0.z, s);
    h = bf2f((unsigned short)a8[3]) + bf2f((unsigned short)b8[3]) + bb0.w;
    s = fmaf(fmaxf(h, 0.f), w0.w, s);
    h = bf2f((unsigned short)a8[4]) + bf2f((unsigned short)b8[4]) + bb1.x;
    s = fmaf(fmaxf(h, 0.f), w1.x, s);
    h = bf2f((unsigned short)a8[5]) + bf2f((unsigned short)b8[5]) + bb1.y;
    s = fmaf(fmaxf(h, 0.f), w1.y, s);
    h = bf2f((unsigned short)a8[6]) + bf2f((unsigned short)b8[6]) + bb1.z;
    s = fmaf(fmaxf(h, 0.f), w1.z, s);
    h = bf2f((unsigned short)a8[7]) + bf2f((unsigned short)b8[7]) + bb1.w;
    s = fmaf(fmaxf(h, 0.f), w1.w, s);
    s += __shfl_xor(s, 1);
    s += __shfl_xor(s, 2);
    s += __shfl_xor(s, 4);
    s += __shfl_xor(s, 8);
    s += __shfl_xor(s, 16);
    s += __shfl_xor(s, 32);
    if (lane == 0) outp[r] = s + b2[c];
}

// ---------------------------------------------------------------------------
extern "C" void kernel_launch(void* const* d_in, const int* in_sizes, int n_in,
                              void* d_out, int out_size, void* d_ws, size_t ws_size,
                              hipStream_t stream) {
    const float* x   = (const float*)d_in[0];
    const int* ei    = (const int*)d_in[1];
    const int* ddb   = (const int*)d_in[2];
    const int* ecl   = (const int*)d_in[3];
    const float* Wg1 = (const float*)d_in[5];
    const float* bg1 = (const float*)d_in[6];
    const float* Wg2 = (const float*)d_in[7];
    const float* bg2 = (const float*)d_in[8];
    const float* W1  = (const float*)d_in[9];
    const float* b1  = (const float*)d_in[10];
    const float* W2  = (const float*)d_in[11];
    const float* b2  = (const float*)d_in[12];
    float* outp = (float*)d_out;

    const size_t NC = (size_t)N_NODES * CDIM;                      // 5.12M elems
    const size_t HRES = (size_t)NUM_DRUGS * HN * sizeof(float);    // 67.1 MB reserved
    // Region 0 (inside reserved extent; all dead before the H GEMM writes Hbf):
    // Hbf (bf16, 33.6 MB) overlaps tmp/t1bf/h1 — all dead at H-GEMM time.
    char* r0 = (char*)d_ws;
    unsigned short* Hbf   = (unsigned short*)d_ws;
    float* tmp            = (float*)r0;
    unsigned short* t1bf  = (unsigned short*)(r0 + 20480000);
    unsigned short* h2bf  = t1bf;
    unsigned short* h1hi  = (unsigned short*)(r0 + 30720000);
    unsigned short* h1lo  = (unsigned short*)(r0 + 40960000);
    unsigned short* xhi   = h1hi;
    unsigned short* xlo   = h1lo;
    char* p = r0 + 51200000;
    auto alloc = [&](size_t bytes) {
        char* r = p;
        p += (bytes + 255) & ~size_t(255);
        return (void*)r;
    };
    float* dinv    = (float*)alloc(sizeof(float) * N_NODES);
    int* cur_d     = (int*)alloc(sizeof(int) * NUM_DRUGS * STRD);
    int* cur_p     = (int*)alloc(sizeof(int) * N_NODES * STRP);
    int* adj_drug  = (int*)alloc(sizeof(int) * NUM_DRUGS * ELLD);
    int* adj_prot  = (int*)alloc(sizeof(int) * (size_t)N_NODES * ELLP);
    // Region 1 (after reserved extent): buffers the H GEMM reads
    p = (char*)d_ws + ((HRES + 255) & ~size_t(255));
    unsigned short* Ghi   = (unsigned short*)alloc(2 * NUM_DRUGS * CDIM);
    unsigned short* Glo   = (unsigned short*)alloc(2 * NUM_DRUGS * CDIM);
    unsigned short* wg1Th = (unsigned short*)alloc(2 * CDIM * CDIM);
    unsigned short* wg1Tl = (unsigned short*)alloc(2 * CDIM * CDIM);
    unsigned short* wg2Th = (unsigned short*)alloc(2 * CDIM * CDIM);
    unsigned short* wg2Tl = (unsigned short*)alloc(2 * CDIM * CDIM);
    unsigned short* W1Th  = (unsigned short*)alloc(2 * (size_t)N_CL * HID * HID);
    unsigned short* W1Tl  = (unsigned short*)alloc(2 * (size_t)N_CL * HID * HID);

    // fused prep: counter zero + x split + Wg transposes + W1 transpose (1 dispatch)
    prep_all<<<NB_T64 + NB_TWG + NB_ZERO + NB_SPLIT, 256, 0, stream>>>(
        x, xhi, xlo, Wg1, Wg2, wg1Th, wg1Tl, wg2Th, wg2Tl, W1, W1Th, W1Tl,
        cur_d, cur_p);
    // ELL fill (needs zeroed counters)
    fill_ell<<<(NUM_DPI + 255) / 256, 256, 0, stream>>>(ei, cur_d, adj_drug,
                                                        cur_p, adj_prot);
    // GCN layer 1 (GEMM also emits bf16 copy for the drug-side gather);
    // dinv computation fused in as 80 extra blocks (blockIdx.x >= 313).
    gemm_mfma<64, 128, 0, 1><<<dim3(MT_NODE + 40, 2), 256, 0, stream>>>(
        xhi, xlo, wg1Th, wg1Tl, tmp, t1bf, N_NODES, CDIM, CDIM,
        MT_NODE, cur_d, cur_p, dinv);
    aggregate1<<<NB_AGG_D + NB_AGG_P, 256, 0, stream>>>(
        tmp, t1bf, cur_d, adj_drug, cur_p, adj_prot, dinv, bg1, h1hi, h1lo);
    // GCN layer 2 (protein rows only downstream)
    gemm_mfma<64, 128, 0, 1><<<dim3(MT_NODE, 2), 256, 0, stream>>>(
        h1hi, h1lo, wg2Th, wg2Tl, tmp, nullptr, N_NODES, CDIM, CDIM,
        MT_NODE, nullptr, nullptr, nullptr);
    aggregate2p<<<(N_PROT * 64 + 255) / 256, 256, 0, stream>>>(
        tmp, cur_p, adj_prot, dinv, bg2, h2bf);
    // pool (bf16 gather, 4 waves/drug) -> split graph embeddings
    pool_drugs<<<NUM_DRUGS, 256, 0, stream>>>(h2bf, Ghi, Glo, cur_d, adj_drug);
    // MLP precompute: Hbf[2048, 8192] (bf16) = G @ W1cat
    // 128x128 tile, SINGLE-buffered 32KB LDS -> 5 blocks/CU (TLP cross-cover),
    // XCD-swizzled (16,64) grid
    gemm_mfma<128, 128, 1, 0><<<dim3(NUM_DRUGS / 128, HN / 128), 256, 0, stream>>>(
        Ghi, Glo, W1Th, W1Tl, nullptr, Hbf, NUM_DRUGS, CDIM, HN,
        NUM_DRUGS / 128, nullptr, nullptr, nullptr);
    // epilogue: gather 2 Hbf rows per batch row, relu+dot, direct store
    mlp_out<<<(BATCH * 64) / 256, 256, 0, stream>>>(Hbf, ddb, ecl, b1, W2, b2, outp);
}

// Round 7
// 249.491 us; speedup vs baseline: 1.0393x; 1.0243x over previous
//
#include <hip/hip_runtime.h>
#include <hip/hip_bf16.h>

// Problem constants (fixed by reference)
#define N_NODES 20000
#define NUM_DRUGS 2048
#define N_PROT (N_NODES - NUM_DRUGS)
#define NUM_DPI 200000
#define E2 400000          // 2*NUM_DPI directed edges
#define CDIM 256           // IN_C == EMB == 256
#define HID 512
#define N_CL 8
#define BATCH 16384
#define HN 8192            // H cols = 8 experts x 2 halves x 512

#define STRD 32            // drug counter padding (ints) = 1 line per counter
#define STRP 16            // protein counter padding
#define ELLD 192           // drug ELL stride (mean deg 97.7, +9.5 sigma)
#define ELLP 48            // protein ELL stride (mean deg 11.1, +11 sigma)

// fused-prep block ranges
#define NB_T64 512         // W1 transpose: 4 x 8 x 16
#define NB_TWG 32          // Wg1/Wg2 transpose: 4 x 4 x 2
#define NB_ZERO 79         // counter zeroing
#define NB_SPLIT 20000     // x split: 5.12M / 256

// node-GEMM tiling (BM=64): 313 row tiles
#define MT_NODE 313

// aggregate1 grid split
#define NB_AGG_D NUM_DRUGS              // 1 block per drug (4 waves)
#define NB_AGG_P ((N_PROT + 3) / 4)     // 4 proteins per block (1 wave each)

typedef __attribute__((ext_vector_type(8))) short short8;   // 8 bf16 (MFMA A/B frag)
typedef __attribute__((ext_vector_type(4))) float floatx4;  // MFMA C/D frag

__device__ inline unsigned short f2bf(float f) {
    unsigned u = __float_as_uint(f);
    u += 0x7fff + ((u >> 16) & 1);   // RNE
    return (unsigned short)(u >> 16);
}
__device__ inline float bf2f(unsigned short h) {
    return __uint_as_float((unsigned)h << 16);
}
__device__ inline void split2(float v, unsigned short& h, unsigned short& l) {
    h = f2bf(v);
    l = f2bf(v - bf2f(h));
}
__device__ inline void gload16(const void* g, void* l) {
    __builtin_amdgcn_global_load_lds(
        (const __attribute__((address_space(1))) void*)g,
        (__attribute__((address_space(3))) void*)l, 16, 0, 0);
}
__device__ inline float4 f4fma(float4 v, float s, float4 a) {
    a.x = fmaf(v.x, s, a.x); a.y = fmaf(v.y, s, a.y);
    a.z = fmaf(v.z, s, a.z); a.w = fmaf(v.w, s, a.w);
    return a;
}
__device__ inline float4 bf4(const unsigned short* p) {
    ushort4 q = *(const ushort4*)p;
    return make_float4(bf2f(q.x), bf2f(q.y), bf2f(q.z), bf2f(q.w));
}

// ---------------------------------------------------------------------------
// Fused prep: W1 transpose-split | Wg1/Wg2 transpose-split | counter zero |
// x split. All mutually independent; one dispatch instead of four.
__global__ __launch_bounds__(256) void prep_all(
        const float* __restrict__ x, unsigned short* __restrict__ xhi,
        unsigned short* __restrict__ xlo,
        const float* __restrict__ Wg1, const float* __restrict__ Wg2,
        unsigned short* __restrict__ wg1Th, unsigned short* __restrict__ wg1Tl,
        unsigned short* __restrict__ wg2Th, unsigned short* __restrict__ wg2Tl,
        const float* __restrict__ W1, unsigned short* __restrict__ W1Th,
        unsigned short* __restrict__ W1Tl,
        int* __restrict__ cur_d, int* __restrict__ cur_p) {
    __shared__ float ld[64 * 65];
    int b = blockIdx.x;
    int t = threadIdx.x;
    int tx = t & 63, ty = t >> 6;
    if (b < NB_T64) {
        // W1 [16 slabs][256][512] -> W1cat^T [8192][256] split bf16
        int m = b >> 5;
        int k0 = (b & 3) * 64, n0 = ((b >> 2) & 7) * 64;
        const float* Wm = W1 + (size_t)m * CDIM * HID;
#pragma unroll
        for (int rr = 0; rr < 16; rr++) {
            int kl = rr * 4 + ty;
            ld[tx * 65 + kl] = Wm[(size_t)(k0 + kl) * HID + n0 + tx];
        }
        __syncthreads();
        size_t obase = (size_t)m * HID * CDIM;
#pragma unroll
        for (int rr = 0; rr < 16; rr++) {
            int nl = rr * 4 + ty;
            float v = ld[nl * 65 + tx];
            unsigned short h, l;
            split2(v, h, l);
            size_t o = obase + (size_t)(n0 + nl) * CDIM + k0 + tx;
            W1Th[o] = h;
            W1Tl[o] = l;
        }
        return;
    }
    b -= NB_T64;
    if (b < NB_TWG) {
        // Wg1/Wg2 [256][256] -> transposed split bf16
        const float* W = (b >> 4) ? Wg2 : Wg1;
        unsigned short* hi = (b >> 4) ? wg2Th : wg1Th;
        unsigned short* lo = (b >> 4) ? wg2Tl : wg1Tl;
        int k0 = (b & 3) * 64, n0 = ((b >> 2) & 3) * 64;
#pragma unroll
        for (int rr = 0; rr < 16; rr++) {
            int kl = rr * 4 + ty;
            ld[tx * 65 + kl] = W[(size_t)(k0 + kl) * CDIM + n0 + tx];
        }
        __syncthreads();
#pragma unroll
        for (int rr = 0; rr < 16; rr++) {
            int nl = rr * 4 + ty;
            float v = ld[nl * 65 + tx];
            unsigned short h, l;
            split2(v, h, l);
            size_t o = (size_t)(n0 + nl) * CDIM + k0 + tx;
            hi[o] = h;
            lo[o] = l;
        }
        return;
    }
    b -= NB_TWG;
    if (b < NB_ZERO) {
        int i = b * 256 + t;
        if (i < N_NODES) cur_p[i * STRP] = 0;
        if (i < NUM_DRUGS) cur_d[i * STRD] = 0;
        return;
    }
    b -= NB_ZERO;
    {   // x split: exactly NB_SPLIT blocks cover 5.12M elems
        int i = b * 256 + t;
        unsigned short h, l;
        split2(x[i], h, l);
        xhi[i] = h;
        xlo[i] = l;
    }
}

// fill both ELL adjacency lists directly (no count/scan passes needed)
__global__ void fill_ell(const int* __restrict__ ei, int* cur_d, int* adj_drug,
                         int* cur_p, int* adj_prot) {
    int e = blockIdx.x * blockDim.x + threadIdx.x;
    if (e >= NUM_DPI) return;
    int d = ei[e];
    int p = ei[E2 + e];
    int posd = atomicAdd(&cur_d[d * STRD], 1);
    int posp = atomicAdd(&cur_p[p * STRP], 1);
    if (posd < ELLD) adj_drug[d * ELLD + posd] = p;   // clamp: never corrupt neighbor
    if (posp < ELLP) adj_prot[(size_t)p * ELLP + posp] = d;
}

// ---------------------------------------------------------------------------
// split-bf16 MFMA GEMM: C[M,N] = A[M,K] @ B[K,N], B passed as B^T ([N][K]).
// Row-major XOR-swizzled LDS; fp32 (C) and/or bf16 (Cbf) outputs, each optional.
// 2-phase prefetch, double-buffered LDS, one vmcnt(0)+barrier pair per K-tile.
// H GEMM note: schedule variants (depth-2 ring, 64x64 5-blk TLP, single-buf)
// all measured 46-55us — per m102's shape curve, ~46us is the structural floor
// of this kernel family at M=2048,K=256. Config reverted to the best-measured
// 128x128 2-phase (R3: 42.9-47.9us).
// Blocks with blockIdx.x >= mTiles run the fused dinv computation instead.
template <int BM, int BN, int SWZ>
__global__ __launch_bounds__(256) void gemm_mfma(
        const unsigned short* __restrict__ Ahi, const unsigned short* __restrict__ Alo,
        const unsigned short* __restrict__ BThi, const unsigned short* __restrict__ BTlo,
        float* __restrict__ C, unsigned short* __restrict__ Cbf,
        int M, int K, int N, int mTiles,
        const int* __restrict__ cur_d, const int* __restrict__ cur_p,
        float* __restrict__ dinv) {
    if ((int)blockIdx.x >= mTiles) {
        int i = (((int)blockIdx.x - mTiles) * (int)gridDim.y + (int)blockIdx.y) * 256
                + (int)threadIdx.x;
        if (i < N_NODES) {
            int deg = (i < NUM_DRUGS) ? cur_d[i * STRD] : cur_p[i * STRP];
            dinv[i] = rsqrtf((float)(deg + 1));
        }
        return;
    }
    constexpr int MI = BM / 32;           // acc row-frags per wave
    constexpr int NJ = BN / 32;           // acc col-frags per wave
    __shared__ unsigned short sAh[2][BM * 32], sAl[2][BM * 32];
    __shared__ unsigned short sBh[2][BN * 32], sBl[2][BN * 32];
    int t = threadIdx.x;
    int wv = t >> 6, lane = t & 63, quad = lane >> 4, l15 = lane & 15;
    int bx = blockIdx.x, by = blockIdx.y;
    if constexpr (SWZ) {
        // H-GEMM grid (16,64): linear id -> XCD k owns col-tiles [8k,8k+8)
        int w = by * 16 + bx;
        int xcd = w & 7, j = w >> 3;
        bx = j & 15;
        by = xcd * 8 + (j >> 4);
    }
    int m0 = bx * BM, n0 = by * BN;
    int m0w = (wv >> 1) * (BM / 2), n0w = (wv & 1) * (BN / 2);
    floatx4 zero = {0.f, 0.f, 0.f, 0.f};
    floatx4 acc[MI][NJ];
#pragma unroll
    for (int i = 0; i < MI; i++)
#pragma unroll
        for (int j = 0; j < NJ; j++) acc[i][j] = zero;

    auto STAGE = [&](int buf, int kk) {
#pragma unroll
        for (int s = t; s < BM * 4; s += 256) {   // A slots
            int row = s >> 2, pos = s & 3;
            int ch = pos ^ ((row >> 1) & 3);      // XOR-swizzled chunk
            int arow = m0 + row; if (arow > M - 1) arow = M - 1;
            size_t aoff = (size_t)arow * K + kk + ch * 8;
            gload16(Ahi + aoff, &sAh[buf][s * 8]);
            gload16(Alo + aoff, &sAl[buf][s * 8]);
        }
#pragma unroll
        for (int s = t; s < BN * 4; s += 256) {   // B slots
            int row = s >> 2, pos = s & 3;
            int ch = pos ^ ((row >> 1) & 3);
            int brow = n0 + row; if (brow > N - 1) brow = N - 1;
            size_t boff = (size_t)brow * K + kk + ch * 8;
            gload16(BThi + boff, &sBh[buf][s * 8]);
            gload16(BTlo + boff, &sBl[buf][s * 8]);
        }
    };

    int nk = K >> 5;
    STAGE(0, 0);
    asm volatile("s_waitcnt vmcnt(0)" ::: "memory");
    __builtin_amdgcn_s_barrier();
    int cur = 0;
    for (int it = 0; it < nk; ++it) {
        if (it + 1 < nk) STAGE(cur ^ 1, (it + 1) << 5);   // prefetch next tile
        short8 ah[MI], al[MI], bh[NJ], bl[NJ];
        int posq = quad ^ ((l15 >> 1) & 3);
#pragma unroll
        for (int i = 0; i < MI; i++) {
            int sl = (m0w + i * 16 + l15) * 4 + posq;
            ah[i] = *(const short8*)&sAh[cur][sl * 8];
            al[i] = *(const short8*)&sAl[cur][sl * 8];
        }
#pragma unroll
        for (int j = 0; j < NJ; j++) {
            int sl = (n0w + j * 16 + l15) * 4 + posq;
            bh[j] = *(const short8*)&sBh[cur][sl * 8];
            bl[j] = *(const short8*)&sBl[cur][sl * 8];
        }
#pragma unroll
        for (int i = 0; i < MI; i++)
#pragma unroll
            for (int j = 0; j < NJ; j++) {
                acc[i][j] = __builtin_amdgcn_mfma_f32_16x16x32_bf16(ah[i], bh[j], acc[i][j], 0, 0, 0);
                acc[i][j] = __builtin_amdgcn_mfma_f32_16x16x32_bf16(ah[i], bl[j], acc[i][j], 0, 0, 0);
                acc[i][j] = __builtin_amdgcn_mfma_f32_16x16x32_bf16(al[i], bh[j], acc[i][j], 0, 0, 0);
            }
        if (it + 1 < nk) {
            asm volatile("s_waitcnt vmcnt(0)" ::: "memory");  // next tile landed
            __builtin_amdgcn_s_barrier();                     // all reads of cur done
            cur ^= 1;
        }
    }
#pragma unroll
    for (int i = 0; i < MI; i++) {
        int gr = m0 + m0w + i * 16 + quad * 4;
#pragma unroll
        for (int r = 0; r < 4; r++) {
            if (gr + r < M) {
#pragma unroll
                for (int j = 0; j < NJ; j++) {
                    size_t o = (size_t)(gr + r) * N + n0 + n0w + j * 16 + l15;
                    float v = acc[i][j][r];
                    if (C) C[o] = v;
                    if (Cbf) Cbf[o] = f2bf(v);
                }
            }
        }
    }
}

// ---------------------------------------------------------------------------
// Layer-1 GCN aggregate — ALL reads bf16 (t1bf): protein-side gather traffic
// halves (200MB -> 100MB fp32->bf16); drug-side was already bf16 and the
// pipeline's stable absmax (2.4e-4 across 7 rounds) shows this noise level is
// within budget. Drug destinations: one BLOCK per drug (4 waves stride-4, LDS
// combine). Protein destinations: one wave each (deg ~11), 4/block.
__global__ __launch_bounds__(256) void aggregate1(const unsigned short* __restrict__ tmpbf,
                                                  const int* __restrict__ cur_d,
                                                  const int* __restrict__ adj_drug,
                                                  const int* __restrict__ cur_p,
                                                  const int* __restrict__ adj_prot,
                                                  const float* __restrict__ dinv,
                                                  const float* __restrict__ bias,
                                                  unsigned short* __restrict__ outhi,
                                                  unsigned short* __restrict__ outlo) {
    __shared__ float4 red[4][64];
    int b = blockIdx.x;
    int lane = threadIdx.x & 63;
    if (b < NB_AGG_D) {
        int d = b;
        int w = threadIdx.x >> 6;
        const int* adj = adj_drug + (size_t)d * ELLD;
        int ecnt = cur_d[d * STRD];
        int e = ecnt < ELLD ? ecnt : ELLD;
        float4 a0 = make_float4(0.f, 0.f, 0.f, 0.f);
        float4 a1 = a0, a2 = a0, a3 = a0;
        int idx = w;
        for (; idx + 12 < e; idx += 16) {
            int j0 = adj[idx], j1 = adj[idx + 4], j2 = adj[idx + 8], j3 = adj[idx + 12];
            float d0 = dinv[j0], d1 = dinv[j1], d2 = dinv[j2], d3 = dinv[j3];
            float4 v0 = bf4(&tmpbf[(size_t)j0 * CDIM + lane * 4]);
            float4 v1 = bf4(&tmpbf[(size_t)j1 * CDIM + lane * 4]);
            float4 v2 = bf4(&tmpbf[(size_t)j2 * CDIM + lane * 4]);
            float4 v3 = bf4(&tmpbf[(size_t)j3 * CDIM + lane * 4]);
            a0 = f4fma(v0, d0, a0);
            a1 = f4fma(v1, d1, a1);
            a2 = f4fma(v2, d2, a2);
            a3 = f4fma(v3, d3, a3);
        }
        for (; idx < e; idx += 4) {
            int j = adj[idx];
            a0 = f4fma(bf4(&tmpbf[(size_t)j * CDIM + lane * 4]), dinv[j], a0);
        }
        a0.x = (a0.x + a1.x) + (a2.x + a3.x);
        a0.y = (a0.y + a1.y) + (a2.y + a3.y);
        a0.z = (a0.z + a1.z) + (a2.z + a3.z);
        a0.w = (a0.w + a1.w) + (a2.w + a3.w);
        red[w][lane] = a0;
        __syncthreads();
        if (w == 0) {
            float di = dinv[d];
            float4 r0 = red[0][lane], r1 = red[1][lane], r2 = red[2][lane], r3 = red[3][lane];
            float4 self = bf4(&tmpbf[(size_t)d * CDIM + lane * 4]);
            float4 acc;
            acc.x = (r0.x + r1.x) + (r2.x + r3.x) + self.x * di;
            acc.y = (r0.y + r1.y) + (r2.y + r3.y) + self.y * di;
            acc.z = (r0.z + r1.z) + (r2.z + r3.z) + self.z * di;
            acc.w = (r0.w + r1.w) + (r2.w + r3.w) + self.w * di;
            float4 bv = ((const float4*)bias)[lane];
            float4 r;
            r.x = fmaxf(fmaf(acc.x, di, bv.x), 0.f);
            r.y = fmaxf(fmaf(acc.y, di, bv.y), 0.f);
            r.z = fmaxf(fmaf(acc.z, di, bv.z), 0.f);
            r.w = fmaxf(fmaf(acc.w, di, bv.w), 0.f);
            ushort4 h, l;
            split2(r.x, h.x, l.x); split2(r.y, h.y, l.y);
            split2(r.z, h.z, l.z); split2(r.w, h.w, l.w);
            *(ushort4*)&outhi[(size_t)d * CDIM + lane * 4] = h;
            *(ushort4*)&outlo[(size_t)d * CDIM + lane * 4] = l;
        }
        return;
    }
    // protein destinations: one wave per node, bf16 gathers
    int i = NUM_DRUGS + (b - NB_AGG_D) * 4 + (threadIdx.x >> 6);
    if (i >= N_NODES) return;
    float di = dinv[i];
    float4 a0 = make_float4(0.f, 0.f, 0.f, 0.f);
    float4 a1 = a0, a2 = a0, a3 = a0;
    const int* adj = adj_prot + (size_t)i * ELLP;
    int e = cur_p[i * STRP];
    int idx = 0;
    for (; idx + 4 <= e; idx += 4) {
        int j0 = adj[idx + 0], j1 = adj[idx + 1];
        int j2 = adj[idx + 2], j3 = adj[idx + 3];
        float d0 = dinv[j0], d1 = dinv[j1], d2 = dinv[j2], d3 = dinv[j3];
        float4 v0 = bf4(&tmpbf[(size_t)j0 * CDIM + lane * 4]);
        float4 v1 = bf4(&tmpbf[(size_t)j1 * CDIM + lane * 4]);
        float4 v2 = bf4(&tmpbf[(size_t)j2 * CDIM + lane * 4]);
        float4 v3 = bf4(&tmpbf[(size_t)j3 * CDIM + lane * 4]);
        a0 = f4fma(v0, d0, a0);
        a1 = f4fma(v1, d1, a1);
        a2 = f4fma(v2, d2, a2);
        a3 = f4fma(v3, d3, a3);
    }
    for (; idx < e; idx++) {
        int j = adj[idx];
        a0 = f4fma(bf4(&tmpbf[(size_t)j * CDIM + lane * 4]), dinv[j], a0);
    }
    float4 self = bf4(&tmpbf[(size_t)i * CDIM + lane * 4]);
    float4 acc;
    acc.x = (a0.x + a1.x) + (a2.x + a3.x) + self.x * di;
    acc.y = (a0.y + a1.y) + (a2.y + a3.y) + self.y * di;
    acc.z = (a0.z + a1.z) + (a2.z + a3.z) + self.z * di;
    acc.w = (a0.w + a1.w) + (a2.w + a3.w) + self.w * di;
    float4 bv = ((const float4*)bias)[lane];
    float4 r;
    r.x = fmaxf(fmaf(acc.x, di, bv.x), 0.f);
    r.y = fmaxf(fmaf(acc.y, di, bv.y), 0.f);
    r.z = fmaxf(fmaf(acc.z, di, bv.z), 0.f);
    r.w = fmaxf(fmaf(acc.w, di, bv.w), 0.f);
    ushort4 h, l;
    split2(r.x, h.x, l.x); split2(r.y, h.y, l.y);
    split2(r.z, h.z, l.z); split2(r.w, h.w, l.w);
    *(ushort4*)&outhi[(size_t)i * CDIM + lane * 4] = h;
    *(ushort4*)&outlo[(size_t)i * CDIM + lane * 4] = l;
}

// Layer-2 GCN aggregate, PROTEIN rows only, bf16 gathers (t2bf).
__global__ __launch_bounds__(256) void aggregate2p(const unsigned short* __restrict__ t2bf,
                                                   const int* __restrict__ cur_p,
                                                   const int* __restrict__ adj_prot,
                                                   const float* __restrict__ dinv,
                                                   const float* __restrict__ bias,
                                                   unsigned short* __restrict__ h2bf) {
    int w = (blockIdx.x * blockDim.x + threadIdx.x) >> 6;
    int lane = threadIdx.x & 63;
    if (w >= N_PROT) return;
    int i = NUM_DRUGS + w;
    float di = dinv[i];
    float4 a0 = make_float4(0.f, 0.f, 0.f, 0.f);
    float4 a1 = a0, a2 = a0, a3 = a0;
    const int* adj = adj_prot + (size_t)i * ELLP;
    int e = cur_p[i * STRP];
    int idx = 0;
    for (; idx + 4 <= e; idx += 4) {
        int j0 = adj[idx + 0], j1 = adj[idx + 1];
        int j2 = adj[idx + 2], j3 = adj[idx + 3];
        float d0 = dinv[j0], d1 = dinv[j1], d2 = dinv[j2], d3 = dinv[j3];
        float4 v0 = bf4(&t2bf[(size_t)j0 * CDIM + lane * 4]);
        float4 v1 = bf4(&t2bf[(size_t)j1 * CDIM + lane * 4]);
        float4 v2 = bf4(&t2bf[(size_t)j2 * CDIM + lane * 4]);
        float4 v3 = bf4(&t2bf[(size_t)j3 * CDIM + lane * 4]);
        a0 = f4fma(v0, d0, a0);
        a1 = f4fma(v1, d1, a1);
        a2 = f4fma(v2, d2, a2);
        a3 = f4fma(v3, d3, a3);
    }
    for (; idx < e; idx++) {
        int j = adj[idx];
        a0 = f4fma(bf4(&t2bf[(size_t)j * CDIM + lane * 4]), dinv[j], a0);
    }
    float4 self = bf4(&t2bf[(size_t)i * CDIM + lane * 4]);
    float4 acc;
    acc.x = (a0.x + a1.x) + (a2.x + a3.x) + self.x * di;
    acc.y = (a0.y + a1.y) + (a2.y + a3.y) + self.y * di;
    acc.z = (a0.z + a1.z) + (a2.z + a3.z) + self.z * di;
    acc.w = (a0.w + a1.w) + (a2.w + a3.w) + self.w * di;
    float4 bv = ((const float4*)bias)[lane];
    ushort4 o;
    o.x = f2bf(fmaxf(fmaf(acc.x, di, bv.x), 0.f));
    o.y = f2bf(fmaxf(fmaf(acc.y, di, bv.y), 0.f));
    o.z = f2bf(fmaxf(fmaf(acc.z, di, bv.z), 0.f));
    o.w = f2bf(fmaxf(fmaf(acc.w, di, bv.w), 0.f));
    *(ushort4*)&h2bf[(size_t)i * CDIM + lane * 4] = o;
}

// scatter-mean pool from bf16 h2 -> split-bf16 graph embeddings.
// One BLOCK per drug: 4 waves split the neighbor list (stride 4), LDS combine.
__global__ __launch_bounds__(256) void pool_drugs(const unsigned short* __restrict__ h2bf,
                                                  unsigned short* __restrict__ Ghi,
                                                  unsigned short* __restrict__ Glo,
                                                  const int* __restrict__ cur_d,
                                                  const int* __restrict__ adj_drug) {
    __shared__ float4 red[4][64];
    int d = blockIdx.x;
    int w = threadIdx.x >> 6, lane = threadIdx.x & 63;
    const int* adj = adj_drug + (size_t)d * ELLD;
    int ecnt = cur_d[d * STRD];
    int e = ecnt < ELLD ? ecnt : ELLD;
    float4 a0 = make_float4(0.f, 0.f, 0.f, 0.f);
    float4 a1 = a0, a2 = a0, a3 = a0;
    int idx = w;
    for (; idx + 12 < e; idx += 16) {
        int j0 = adj[idx], j1 = adj[idx + 4], j2 = adj[idx + 8], j3 = adj[idx + 12];
        float4 v0 = bf4(&h2bf[(size_t)j0 * CDIM + lane * 4]);
        float4 v1 = bf4(&h2bf[(size_t)j1 * CDIM + lane * 4]);
        float4 v2 = bf4(&h2bf[(size_t)j2 * CDIM + lane * 4]);
        float4 v3 = bf4(&h2bf[(size_t)j3 * CDIM + lane * 4]);
        a0.x += v0.x; a0.y += v0.y; a0.z += v0.z; a0.w += v0.w;
        a1.x += v1.x; a1.y += v1.y; a1.z += v1.z; a1.w += v1.w;
        a2.x += v2.x; a2.y += v2.y; a2.z += v2.z; a2.w += v2.w;
        a3.x += v3.x; a3.y += v3.y; a3.z += v3.z; a3.w += v3.w;
    }
    for (; idx < e; idx += 4) {
        float4 v = bf4(&h2bf[(size_t)adj[idx] * CDIM + lane * 4]);
        a0.x += v.x; a0.y += v.y; a0.z += v.z; a0.w += v.w;
    }
    a0.x = (a0.x + a1.x) + (a2.x + a3.x);
    a0.y = (a0.y + a1.y) + (a2.y + a3.y);
    a0.z = (a0.z + a1.z) + (a2.z + a3.z);
    a0.w = (a0.w + a1.w) + (a2.w + a3.w);
    red[w][lane] = a0;
    __syncthreads();
    if (w == 0) {
        float4 r0 = red[0][lane], r1 = red[1][lane], r2 = red[2][lane], r3 = red[3][lane];
        float4 acc;
        acc.x = (r0.x + r1.x) + (r2.x + r3.x);
        acc.y = (r0.y + r1.y) + (r2.y + r3.y);
        acc.z = (r0.z + r1.z) + (r2.z + r3.z);
        acc.w = (r0.w + r1.w) + (r2.w + r3.w);
        float sc = 1.f / (float)(ecnt > 1 ? ecnt : 1);
        acc.x *= sc; acc.y *= sc; acc.z *= sc; acc.w *= sc;
        ushort4 h, l;
        split2(acc.x, h.x, l.x); split2(acc.y, h.y, l.y);
        split2(acc.z, h.z, l.z); split2(acc.w, h.w, l.w);
        *(ushort4*)&Ghi[(size_t)d * CDIM + lane * 4] = h;
        *(ushort4*)&Glo[(size_t)d * CDIM + lane * 4] = l;
    }
}

// ---------------------------------------------------------------------------
// MLP epilogue: out[r] = sum_n relu(H[d0][2c*512+n] + H[d1][(2c+1)*512+n]
//                                   + b1[c][n]) * W2[c][n] + b2[c]
// H in bf16; one wave per row; lane covers 8 cols -> single pass, 16B loads.
__global__ __launch_bounds__(256) void mlp_out(const unsigned short* __restrict__ Hbf,
                                               const int* __restrict__ ddb,
                                               const int* __restrict__ ecl,
                                               const float* __restrict__ b1,
                                               const float* __restrict__ W2,
                                               const float* __restrict__ b2,
                                               float* __restrict__ outp) {
    int r = (blockIdx.x * blockDim.x + threadIdx.x) >> 6;
    int lane = threadIdx.x & 63;
    if (r >= BATCH) return;
    int c = ecl[r];
    int d0 = ddb[r], d1 = ddb[BATCH + r];
    int n = lane * 8;
    const unsigned short* h0 = Hbf + (size_t)d0 * HN + (size_t)(c * 2) * HID + n;
    const unsigned short* h1 = Hbf + (size_t)d1 * HN + (size_t)(c * 2 + 1) * HID + n;
    const float* b1e = b1 + (size_t)c * HID + n;
    const float* w2e = W2 + (size_t)c * HID + n;
    short8 a8 = *(const short8*)h0;
    short8 b8 = *(const short8*)h1;
    float4 bb0 = *(const float4*)(b1e);
    float4 bb1 = *(const float4*)(b1e + 4);
    float4 w0 = *(const float4*)(w2e);
    float4 w1 = *(const float4*)(w2e + 4);
    float s = 0.f;
    float h;
    h = bf2f((unsigned short)a8[0]) + bf2f((unsigned short)b8[0]) + bb0.x;
    s = fmaf(fmaxf(h, 0.f), w0.x, s);
    h = bf2f((unsigned short)a8[1]) + bf2f((unsigned short)b8[1]) + bb0.y;
    s = fmaf(fmaxf(h, 0.f), w0.y, s);
    h = bf2f((unsigned short)a8[2]) + bf2f((unsigned short)b8[2]) + bb0.z;
    s = fmaf(fmaxf(h, 0.f), w0.z, s);
    h = bf2f((unsigned short)a8[3]) + bf2f((unsigned short)b8[3]) + bb0.w;
    s = fmaf(fmaxf(h, 0.f), w0.w, s);
    h = bf2f((unsigned short)a8[4]) + bf2f((unsigned short)b8[4]) + bb1.x;
    s = fmaf(fmaxf(h, 0.f), w1.x, s);
    h = bf2f((unsigned short)a8[5]) + bf2f((unsigned short)b8[5]) + bb1.y;
    s = fmaf(fmaxf(h, 0.f), w1.y, s);
    h = bf2f((unsigned short)a8[6]) + bf2f((unsigned short)b8[6]) + bb1.z;
    s = fmaf(fmaxf(h, 0.f), w1.z, s);
    h = bf2f((unsigned short)a8[7]) + bf2f((unsigned short)b8[7]) + bb1.w;
    s = fmaf(fmaxf(h, 0.f), w1.w, s);
    s += __shfl_xor(s, 1);
    s += __shfl_xor(s, 2);
    s += __shfl_xor(s, 4);
    s += __shfl_xor(s, 8);
    s += __shfl_xor(s, 16);
    s += __shfl_xor(s, 32);
    if (lane == 0) outp[r] = s + b2[c];
}

// ---------------------------------------------------------------------------
extern "C" void kernel_launch(void* const* d_in, const int* in_sizes, int n_in,
                              void* d_out, int out_size, void* d_ws, size_t ws_size,
                              hipStream_t stream) {
    const float* x   = (const float*)d_in[0];
    const int* ei    = (const int*)d_in[1];
    const int* ddb   = (const int*)d_in[2];
    const int* ecl   = (const int*)d_in[3];
    const float* Wg1 = (const float*)d_in[5];
    const float* bg1 = (const float*)d_in[6];
    const float* Wg2 = (const float*)d_in[7];
    const float* bg2 = (const float*)d_in[8];
    const float* W1  = (const float*)d_in[9];
    const float* b1  = (const float*)d_in[10];
    const float* W2  = (const float*)d_in[11];
    const float* b2  = (const float*)d_in[12];
    float* outp = (float*)d_out;

    const size_t NC = (size_t)N_NODES * CDIM;                      // 5.12M elems
    const size_t HRES = (size_t)NUM_DRUGS * HN * sizeof(float);    // 67.1 MB reserved
    // Region 0 (inside reserved extent; all dead before the H GEMM writes Hbf):
    // Hbf (bf16, 33.6 MB) overlaps t2bf/t1bf/h1 — all dead at H-GEMM time.
    char* r0 = (char*)d_ws;
    unsigned short* Hbf   = (unsigned short*)d_ws;
    unsigned short* t2bf  = (unsigned short*)r0;                   // 10.24 MB
    unsigned short* t1bf  = (unsigned short*)(r0 + 20480000);
    unsigned short* h2bf  = t1bf;
    unsigned short* h1hi  = (unsigned short*)(r0 + 30720000);
    unsigned short* h1lo  = (unsigned short*)(r0 + 40960000);
    unsigned short* xhi   = h1hi;
    unsigned short* xlo   = h1lo;
    char* p = r0 + 51200000;
    auto alloc = [&](size_t bytes) {
        char* r = p;
        p += (bytes + 255) & ~size_t(255);
        return (void*)r;
    };
    float* dinv    = (float*)alloc(sizeof(float) * N_NODES);
    int* cur_d     = (int*)alloc(sizeof(int) * NUM_DRUGS * STRD);
    int* cur_p     = (int*)alloc(sizeof(int) * N_NODES * STRP);
    int* adj_drug  = (int*)alloc(sizeof(int) * NUM_DRUGS * ELLD);
    int* adj_prot  = (int*)alloc(sizeof(int) * (size_t)N_NODES * ELLP);
    // Region 1 (after reserved extent): buffers the H GEMM reads
    p = (char*)d_ws + ((HRES + 255) & ~size_t(255));
    unsigned short* Ghi   = (unsigned short*)alloc(2 * NUM_DRUGS * CDIM);
    unsigned short* Glo   = (unsigned short*)alloc(2 * NUM_DRUGS * CDIM);
    unsigned short* wg1Th = (unsigned short*)alloc(2 * CDIM * CDIM);
    unsigned short* wg1Tl = (unsigned short*)alloc(2 * CDIM * CDIM);
    unsigned short* wg2Th = (unsigned short*)alloc(2 * CDIM * CDIM);
    unsigned short* wg2Tl = (unsigned short*)alloc(2 * CDIM * CDIM);
    unsigned short* W1Th  = (unsigned short*)alloc(2 * (size_t)N_CL * HID * HID);
    unsigned short* W1Tl  = (unsigned short*)alloc(2 * (size_t)N_CL * HID * HID);

    // fused prep: counter zero + x split + Wg transposes + W1 transpose (1 dispatch)
    prep_all<<<NB_T64 + NB_TWG + NB_ZERO + NB_SPLIT, 256, 0, stream>>>(
        x, xhi, xlo, Wg1, Wg2, wg1Th, wg1Tl, wg2Th, wg2Tl, W1, W1Th, W1Tl,
        cur_d, cur_p);
    // ELL fill (needs zeroed counters)
    fill_ell<<<(NUM_DPI + 255) / 256, 256, 0, stream>>>(ei, cur_d, adj_drug,
                                                        cur_p, adj_prot);
    // GCN layer 1: bf16-only output (t1bf); dinv fused as 80 extra blocks.
    gemm_mfma<64, 128, 0><<<dim3(MT_NODE + 40, 2), 256, 0, stream>>>(
        xhi, xlo, wg1Th, wg1Tl, nullptr, t1bf, N_NODES, CDIM, CDIM,
        MT_NODE, cur_d, cur_p, dinv);
    aggregate1<<<NB_AGG_D + NB_AGG_P, 256, 0, stream>>>(
        t1bf, cur_d, adj_drug, cur_p, adj_prot, dinv, bg1, h1hi, h1lo);
    // GCN layer 2: bf16-only output (t2bf); protein rows only downstream.
    gemm_mfma<64, 128, 0><<<dim3(MT_NODE, 2), 256, 0, stream>>>(
        h1hi, h1lo, wg2Th, wg2Tl, nullptr, t2bf, N_NODES, CDIM, CDIM,
        MT_NODE, nullptr, nullptr, nullptr);
    aggregate2p<<<(N_PROT * 64 + 255) / 256, 256, 0, stream>>>(
        t2bf, cur_p, adj_prot, dinv, bg2, h2bf);
    // pool (bf16 gather, 4 waves/drug) -> split graph embeddings
    pool_drugs<<<NUM_DRUGS, 256, 0, stream>>>(h2bf, Ghi, Glo, cur_d, adj_drug);
    // MLP precompute: Hbf[2048, 8192] (bf16) = G @ W1cat
    // 128x128 2-phase dbuf (best-measured config), XCD-swizzled (16,64) grid
    gemm_mfma<128, 128, 1><<<dim3(NUM_DRUGS / 128, HN / 128), 256, 0, stream>>>(
        Ghi, Glo, W1Th, W1Tl, nullptr, Hbf, NUM_DRUGS, CDIM, HN,
        NUM_DRUGS / 128, nullptr, nullptr, nullptr);
    // epilogue: gather 2 Hbf rows per batch row, relu+dot, direct store
    mlp_out<<<(BATCH * 64) / 256, 256, 0, stream>>>(Hbf, ddb, ecl, b1, W2, b2, outp);
}